// Round 2
// baseline (685.681 us; speedup 1.0000x reference)
//
#include <hip/hip_runtime.h>
#include <hip/hip_bf16.h>

#define NNODES 50000
#define NEDGES 800000
#define ETOT   850000
#define NEG_SLOPE 0.2f
#define LN_EPS 1e-5f
#define SM_EPS 1e-16f

__device__ __forceinline__ float lrelu(float x) { return x > 0.f ? x : NEG_SLOPE * x; }

// ---------------- CSR build ----------------
__global__ void k_hist(const int* __restrict__ ei, int* __restrict__ deg) {
    int e = blockIdx.x * 256 + threadIdx.x;
    if (e >= ETOT) return;
    int dst = (e < NEDGES) ? ei[NEDGES + e] : (e - NEDGES);
    atomicAdd(&deg[dst], 1);
}

__global__ void k_scan1(const int* __restrict__ deg, int* __restrict__ rowstart,
                        int* __restrict__ blocksum) {
    __shared__ int s[256];
    int t = threadIdx.x;
    int i = blockIdx.x * 256 + t;
    int v = (i < NNODES) ? deg[i] : 0;
    s[t] = v;
    __syncthreads();
    #pragma unroll
    for (int off = 1; off < 256; off <<= 1) {
        int add = (t >= off) ? s[t - off] : 0;
        __syncthreads();
        s[t] += add;
        __syncthreads();
    }
    if (i < NNODES) rowstart[i] = s[t] - v;   // exclusive within block
    if (t == 255) blocksum[blockIdx.x] = s[255];
}

__global__ void k_scan2(int* __restrict__ bs, int nb) {
    __shared__ int s[256];
    int t = threadIdx.x;
    int v = (t < nb) ? bs[t] : 0;
    s[t] = v;
    __syncthreads();
    #pragma unroll
    for (int off = 1; off < 256; off <<= 1) {
        int add = (t >= off) ? s[t - off] : 0;
        __syncthreads();
        s[t] += add;
        __syncthreads();
    }
    if (t < nb) bs[t] = s[t] - v;             // exclusive block offsets
}

__global__ void k_scan3(int* __restrict__ rowstart, const int* __restrict__ boff,
                        int* __restrict__ cursor) {
    int i = blockIdx.x * 256 + threadIdx.x;
    if (i < NNODES) {
        int r = rowstart[i] + boff[i >> 8];
        rowstart[i] = r;
        cursor[i] = r;
    } else if (i == NNODES) {
        rowstart[NNODES] = ETOT;
    }
}

__global__ void k_scatter(const int* __restrict__ ei, int* __restrict__ cursor,
                          int* __restrict__ csr_src) {
    int e = blockIdx.x * 256 + threadIdx.x;
    if (e >= ETOT) return;
    int src, dst;
    if (e < NEDGES) { src = ei[e]; dst = ei[NEDGES + e]; }
    else { src = e - NEDGES; dst = src; }
    int pos = atomicAdd(&cursor[dst], 1);
    csr_src[pos] = src;
}

// ---------------- tiled GEMM: C[M,NC] = A[M,K] @ B[K,NC], fp32 ----------------
#define BM 64
#define BN 64
#define BK 32
#define LDP 68   // padded LDS leading dim (floats): 16B-aligned float4 reads, conflict-light

__global__ __launch_bounds__(256) void k_gemm(const float* __restrict__ A,
                                              const float* __restrict__ B,
                                              float* __restrict__ C, int M, int K, int NC) {
    __shared__ float As[BK * LDP];  // As[k][m]
    __shared__ float Bs[BK * LDP];  // Bs[k][n]
    const int t = threadIdx.x;
    const int m0 = blockIdx.x * BM;
    const int n0 = blockIdx.y * BN;
    const int tx = t & 15, ty = t >> 4;
    float acc[4][4] = {};
    for (int k0 = 0; k0 < K; k0 += BK) {
        #pragma unroll
        for (int it = 0; it < 8; ++it) {          // stage A tile: 64 rows x 32 cols
            int f = t + 256 * it;
            int r = f >> 5, c = f & 31;
            int row = m0 + r;
            float v = 0.f;
            if (row < M) v = A[(size_t)row * K + k0 + c];
            As[c * LDP + r] = v;
        }
        #pragma unroll
        for (int it = 0; it < 8; ++it) {          // stage B tile: 32 rows x 64 cols
            int f = t + 256 * it;
            int kr = f >> 6, c = f & 63;
            Bs[kr * LDP + c] = B[(size_t)(k0 + kr) * NC + n0 + c];
        }
        __syncthreads();
        #pragma unroll
        for (int k = 0; k < BK; ++k) {
            const float4 av = *reinterpret_cast<const float4*>(&As[k * LDP + ty * 4]);
            const float4 bv = *reinterpret_cast<const float4*>(&Bs[k * LDP + tx * 4]);
            float ar[4] = {av.x, av.y, av.z, av.w};
            float br[4] = {bv.x, bv.y, bv.z, bv.w};
            #pragma unroll
            for (int mi = 0; mi < 4; ++mi)
                #pragma unroll
                for (int ni = 0; ni < 4; ++ni)
                    acc[mi][ni] = fmaf(ar[mi], br[ni], acc[mi][ni]);
        }
        __syncthreads();
    }
    #pragma unroll
    for (int mi = 0; mi < 4; ++mi) {
        int row = m0 + ty * 4 + mi;
        if (row < M) {
            float4 o = make_float4(acc[mi][0], acc[mi][1], acc[mi][2], acc[mi][3]);
            *reinterpret_cast<float4*>(&C[(size_t)row * NC + n0 + tx * 4]) = o;
        }
    }
}

// ---------------- layer 1: fused logits + online softmax + aggregate + head-mean + LN + ReLU
// wave per node; lane holds features lane*4..lane*4+3 of the 256 (head = lane/16)
__global__ void k_node1(const float* __restrict__ xl, const float* __restrict__ xr,
                        const int* __restrict__ rowstart, const int* __restrict__ csr_src,
                        const float* __restrict__ att,   // [4,64]
                        const float* __restrict__ bias,  // [64]
                        const float* __restrict__ lng,
                        const float* __restrict__ lnb,
                        float* __restrict__ hout) {
    int wid = (blockIdx.x * 256 + threadIdx.x) >> 6;
    int lane = threadIdx.x & 63;
    if (wid >= NNODES) return;
    const int i = wid;
    const int grp = lane >> 4;       // head
    const int c0 = (lane & 15) * 4;  // channel base within head
    const int fb = lane * 4;         // feature base (= grp*64 + c0)

    const float4 xrv = *reinterpret_cast<const float4*>(xr + (size_t)i * 256 + fb);
    const float4 av4 = *reinterpret_cast<const float4*>(att + fb);
    float a0 = av4.x, a1 = av4.y, a2 = av4.z, a3 = av4.w;

    float m = -1e30f, l = 0.f;
    float acc0 = 0.f, acc1 = 0.f, acc2 = 0.f, acc3 = 0.f;
    const int p1 = rowstart[i + 1];
    for (int p = rowstart[i]; p < p1; ++p) {
        int j = csr_src[p];
        const float4 xlv = *reinterpret_cast<const float4*>(xl + (size_t)j * 256 + fb);
        float t0 = lrelu(xlv.x + xrv.x);
        float t1 = lrelu(xlv.y + xrv.y);
        float t2 = lrelu(xlv.z + xrv.z);
        float t3 = lrelu(xlv.w + xrv.w);
        float e = t0 * a0 + t1 * a1 + t2 * a2 + t3 * a3;
        e += __shfl_xor(e, 1);
        e += __shfl_xor(e, 2);
        e += __shfl_xor(e, 4);
        e += __shfl_xor(e, 8);       // e = per-head logit, broadcast in 16-lane group
        float mn = fmaxf(m, e);
        float sc = __expf(m - mn);
        float pe = __expf(e - mn);
        l = l * sc + pe;
        acc0 = acc0 * sc + pe * xlv.x;
        acc1 = acc1 * sc + pe * xlv.y;
        acc2 = acc2 * sc + pe * xlv.z;
        acc3 = acc3 * sc + pe * xlv.w;
        m = mn;
    }
    float inv = 1.f / (l + SM_EPS);
    float v0 = acc0 * inv, v1 = acc1 * inv, v2 = acc2 * inv, v3 = acc3 * inv;
    // mean over 4 heads (lanes l, l^16, l^32, l^48 hold same channels)
    v0 += __shfl_xor(v0, 16); v0 += __shfl_xor(v0, 32);
    v1 += __shfl_xor(v1, 16); v1 += __shfl_xor(v1, 32);
    v2 += __shfl_xor(v2, 16); v2 += __shfl_xor(v2, 32);
    v3 += __shfl_xor(v3, 16); v3 += __shfl_xor(v3, 32);
    float o0 = v0 * 0.25f + bias[c0 + 0];
    float o1 = v1 * 0.25f + bias[c0 + 1];
    float o2 = v2 * 0.25f + bias[c0 + 2];
    float o3 = v3 * 0.25f + bias[c0 + 3];
    // LayerNorm over 64 channels (each 16-lane group holds a full replica)
    float s = o0 + o1 + o2 + o3;
    s += __shfl_xor(s, 1); s += __shfl_xor(s, 2); s += __shfl_xor(s, 4); s += __shfl_xor(s, 8);
    float mu = s * 0.015625f;
    float d0 = o0 - mu, d1 = o1 - mu, d2 = o2 - mu, d3 = o3 - mu;
    float ss = d0 * d0 + d1 * d1 + d2 * d2 + d3 * d3;
    ss += __shfl_xor(ss, 1); ss += __shfl_xor(ss, 2); ss += __shfl_xor(ss, 4); ss += __shfl_xor(ss, 8);
    float istd = rsqrtf(ss * 0.015625f + LN_EPS);
    float h0 = fmaxf(d0 * istd * lng[c0 + 0] + lnb[c0 + 0], 0.f);
    float h1v = fmaxf(d1 * istd * lng[c0 + 1] + lnb[c0 + 1], 0.f);
    float h2 = fmaxf(d2 * istd * lng[c0 + 2] + lnb[c0 + 2], 0.f);
    float h3 = fmaxf(d3 * istd * lng[c0 + 3] + lnb[c0 + 3], 0.f);
    if (grp == 0) {
        float4 o = make_float4(h0, h1v, h2, h3);
        *reinterpret_cast<float4*>(hout + (size_t)i * 64 + c0) = o;
    }
}

// ---------------- layer 2: per-node fused, 1 head, final LN, fp32 out ----------------
__global__ void k_node2(const float* __restrict__ xl, const float* __restrict__ xr,
                        const int* __restrict__ rowstart, const int* __restrict__ csr_src,
                        const float* __restrict__ att,   // [64]
                        const float* __restrict__ bias,
                        const float* __restrict__ lng,
                        const float* __restrict__ lnb,
                        float* __restrict__ out) {
    int wid = (blockIdx.x * 256 + threadIdx.x) >> 6;
    int lane = threadIdx.x & 63;
    if (wid >= NNODES) return;
    const int i = wid;
    float xrv = xr[(size_t)i * 64 + lane];
    float a = att[lane];
    float m = -1e30f, l = 0.f, acc = 0.f;
    const int p1 = rowstart[i + 1];
    for (int p = rowstart[i]; p < p1; ++p) {
        int j = csr_src[p];
        float xlv = xl[(size_t)j * 64 + lane];
        float e = lrelu(xlv + xrv) * a;
        e += __shfl_xor(e, 1); e += __shfl_xor(e, 2); e += __shfl_xor(e, 4);
        e += __shfl_xor(e, 8); e += __shfl_xor(e, 16); e += __shfl_xor(e, 32);
        float mn = fmaxf(m, e);
        float sc = __expf(m - mn);
        float pe = __expf(e - mn);
        l = l * sc + pe;
        acc = acc * sc + pe * xlv;
        m = mn;
    }
    float v = acc / (l + SM_EPS) + bias[lane];
    float s = v;
    s += __shfl_xor(s, 1); s += __shfl_xor(s, 2); s += __shfl_xor(s, 4);
    s += __shfl_xor(s, 8); s += __shfl_xor(s, 16); s += __shfl_xor(s, 32);
    float mu = s * 0.015625f;
    float d = v - mu;
    float ss = d * d;
    ss += __shfl_xor(ss, 1); ss += __shfl_xor(ss, 2); ss += __shfl_xor(ss, 4);
    ss += __shfl_xor(ss, 8); ss += __shfl_xor(ss, 16); ss += __shfl_xor(ss, 32);
    float istd = rsqrtf(ss * 0.015625f + LN_EPS);
    float y = d * istd * lng[lane] + lnb[lane];
    out[(size_t)i * 64 + lane] = y;
}

extern "C" void kernel_launch(void* const* d_in, const int* in_sizes, int n_in,
                              void* d_out, int out_size, void* d_ws, size_t ws_size,
                              hipStream_t stream) {
    const float* x    = (const float*)d_in[0];
    const int*   ei   = (const int*)d_in[1];
    const float* W1l  = (const float*)d_in[2];
    const float* W1r  = (const float*)d_in[3];
    const float* att1 = (const float*)d_in[4];
    const float* b1   = (const float*)d_in[5];
    const float* ln1g = (const float*)d_in[6];
    const float* ln1b = (const float*)d_in[7];
    const float* W2l  = (const float*)d_in[8];
    const float* W2r  = (const float*)d_in[9];
    const float* att2 = (const float*)d_in[10];
    const float* b2   = (const float*)d_in[11];
    const float* ln2g = (const float*)d_in[12];
    const float* ln2b = (const float*)d_in[13];
    float* out = (float*)d_out;

    char* w = (char*)d_ws;
    size_t off = 0;
    auto alloc = [&](size_t bytes) -> void* {
        void* p = w + off;
        off += (bytes + 255) & ~(size_t)255;
        return p;
    };
    float* xl1     = (float*)alloc((size_t)NNODES * 256 * 4);  // freed after k_node1
    float* xr1     = (float*)alloc((size_t)NNODES * 256 * 4);
    float* h1      = (float*)alloc((size_t)NNODES * 64 * 4);
    int* deg       = (int*)alloc((size_t)NNODES * 4);
    int* rowstart  = (int*)alloc((size_t)(NNODES + 1) * 4);
    int* cursor    = (int*)alloc((size_t)NNODES * 4);
    int* csr_src   = (int*)alloc((size_t)ETOT * 4);
    int* blocksum  = (int*)alloc(1024);
    // xl2/xr2 alias the (dead after k_node1) xl1 region
    float* xl2     = xl1;
    float* xr2     = xl1 + (size_t)NNODES * 64;
    (void)ws_size; (void)in_sizes; (void)n_in; (void)out_size;

    hipMemsetAsync(deg, 0, (size_t)NNODES * 4, stream);
    const int histB = (ETOT + 255) / 256;
    const int scanB = (NNODES + 255) / 256;
    k_hist<<<histB, 256, 0, stream>>>(ei, deg);
    k_scan1<<<scanB, 256, 0, stream>>>(deg, rowstart, blocksum);
    k_scan2<<<1, 256, 0, stream>>>(blocksum, scanB);
    k_scan3<<<scanB, 256, 0, stream>>>(rowstart, blocksum, cursor);
    k_scatter<<<histB, 256, 0, stream>>>(ei, cursor, csr_src);

    dim3 g1((NNODES + BM - 1) / BM, 256 / BN);   // (782, 4)
    k_gemm<<<g1, 256, 0, stream>>>(x, W1l, xl1, NNODES, 256, 256);
    k_gemm<<<g1, 256, 0, stream>>>(x, W1r, xr1, NNODES, 256, 256);
    k_node1<<<(NNODES + 3) / 4, 256, 0, stream>>>(xl1, xr1, rowstart, csr_src,
                                                  att1, b1, ln1g, ln1b, h1);
    dim3 g2((NNODES + BM - 1) / BM, 1);
    k_gemm<<<g2, 256, 0, stream>>>(h1, W2l, xl2, NNODES, 64, 64);
    k_gemm<<<g2, 256, 0, stream>>>(h1, W2r, xr2, NNODES, 64, 64);
    k_node2<<<(NNODES + 3) / 4, 256, 0, stream>>>(xl2, xr2, rowstart, csr_src,
                                                  att2, b2, ln2g, ln2b, out);
}

// Round 3
// 530.069 us; speedup vs baseline: 1.2936x; 1.2936x over previous
//
#include <hip/hip_runtime.h>
#include <hip/hip_bf16.h>

#define NNODES 50000
#define NEDGES 800000
#define ETOT   850000
#define NEG_SLOPE 0.2f
#define LN_EPS 1e-5f
#define SM_EPS 1e-16f

typedef short bf16x8 __attribute__((ext_vector_type(8)));
typedef float f32x4  __attribute__((ext_vector_type(4)));

__device__ __forceinline__ float lrelu(float x) { return x > 0.f ? x : NEG_SLOPE * x; }

__device__ __forceinline__ float4 ldbf4(const __hip_bfloat16* p) {
    // 4 consecutive bf16 (8B aligned) -> float4
    uint2 raw = *reinterpret_cast<const uint2*>(p);
    __hip_bfloat162 ab = *reinterpret_cast<__hip_bfloat162*>(&raw.x);
    __hip_bfloat162 cd = *reinterpret_cast<__hip_bfloat162*>(&raw.y);
    float2 f0 = __bfloat1622float2(ab);
    float2 f1 = __bfloat1622float2(cd);
    return make_float4(f0.x, f0.y, f1.x, f1.y);
}

// ---------------- casts ----------------
__global__ void k_cast_x(const float* __restrict__ X, __hip_bfloat16* __restrict__ Y, int n4) {
    int i = blockIdx.x * 256 + threadIdx.x;
    if (i >= n4) return;
    float4 v = reinterpret_cast<const float4*>(X)[i];
    __hip_bfloat162 lo, hi;
    lo.x = __float2bfloat16(v.x); lo.y = __float2bfloat16(v.y);
    hi.x = __float2bfloat16(v.z); hi.y = __float2bfloat16(v.w);
    reinterpret_cast<__hip_bfloat162*>(Y)[2 * i]     = lo;
    reinterpret_cast<__hip_bfloat162*>(Y)[2 * i + 1] = hi;
}

// W[k][n] fp32 (256x256) -> WT[n][k] bf16
__global__ void k_cast_wT(const float* __restrict__ W, __hip_bfloat16* __restrict__ WT) {
    int t = blockIdx.x * 256 + threadIdx.x;
    if (t >= 256 * 256) return;
    int k = t >> 8, n = t & 255;
    WT[n * 256 + k] = __float2bfloat16(W[t]);
}

// ---------------- CSR build ----------------
__global__ void k_hist(const int* __restrict__ ei, int* __restrict__ deg) {
    int e = blockIdx.x * 256 + threadIdx.x;
    if (e >= ETOT) return;
    int dst = (e < NEDGES) ? ei[NEDGES + e] : (e - NEDGES);
    atomicAdd(&deg[dst], 1);
}

__global__ void k_scan1(const int* __restrict__ deg, int* __restrict__ rowstart,
                        int* __restrict__ blocksum) {
    __shared__ int s[256];
    int t = threadIdx.x;
    int i = blockIdx.x * 256 + t;
    int v = (i < NNODES) ? deg[i] : 0;
    s[t] = v;
    __syncthreads();
    #pragma unroll
    for (int off = 1; off < 256; off <<= 1) {
        int add = (t >= off) ? s[t - off] : 0;
        __syncthreads();
        s[t] += add;
        __syncthreads();
    }
    if (i < NNODES) rowstart[i] = s[t] - v;
    if (t == 255) blocksum[blockIdx.x] = s[255];
}

__global__ void k_scan2(int* __restrict__ bs, int nb) {
    __shared__ int s[256];
    int t = threadIdx.x;
    int v = (t < nb) ? bs[t] : 0;
    s[t] = v;
    __syncthreads();
    #pragma unroll
    for (int off = 1; off < 256; off <<= 1) {
        int add = (t >= off) ? s[t - off] : 0;
        __syncthreads();
        s[t] += add;
        __syncthreads();
    }
    if (t < nb) bs[t] = s[t] - v;
}

__global__ void k_scan3(int* __restrict__ rowstart, const int* __restrict__ boff,
                        int* __restrict__ cursor) {
    int i = blockIdx.x * 256 + threadIdx.x;
    if (i < NNODES) {
        int r = rowstart[i] + boff[i >> 8];
        rowstart[i] = r;
        cursor[i] = r;
    } else if (i == NNODES) {
        rowstart[NNODES] = ETOT;
    }
}

__global__ void k_scatter(const int* __restrict__ ei, int* __restrict__ cursor,
                          int* __restrict__ csr_src) {
    int e = blockIdx.x * 256 + threadIdx.x;
    if (e >= ETOT) return;
    int src, dst;
    if (e < NEDGES) { src = ei[e]; dst = ei[NEDGES + e]; }
    else { src = e - NEDGES; dst = src; }
    int pos = atomicAdd(&cursor[dst], 1);
    csr_src[pos] = src;
}

// ---------------- MFMA bf16 GEMM: C[M,256] = A[M,256] @ WT^T, out bf16 ----------------
// WT is [256 n][256 k] (transposed weights). Tile 128x64, block=4 waves.
#define GBM 128
#define GBN 64
#define LDA 72    // shorts per As row (64 + 8 pad): frag reads 2-way conflict (free)
#define LDB 264   // shorts per Bs row (256 + 8 pad)

__global__ __launch_bounds__(256) void k_gemm_mfma(
    const __hip_bfloat16* __restrict__ A,
    const __hip_bfloat16* __restrict__ WT,
    __hip_bfloat16* __restrict__ C, int M)
{
    __shared__ short As[GBM * LDA];   // 18.0 KB
    __shared__ short Bs[GBN * LDB];   // 33.0 KB (full-K weight panel)
    const int t = threadIdx.x;
    const int m0 = blockIdx.x * GBM;
    const int n0 = blockIdx.y * GBN;
    const int wave = t >> 6, lane = t & 63;
    const int wm = wave & 1, wn = wave >> 1;
    const int l15 = lane & 15, quad = lane >> 4;

    // stage full B panel once: rows n0..n0+63, all K
    #pragma unroll
    for (int it = 0; it < 8; ++it) {
        int f = t + 256 * it;
        int n = f >> 5, c = (f & 31) * 8;
        *reinterpret_cast<uint4*>(&Bs[n * LDB + c]) =
            *reinterpret_cast<const uint4*>(&WT[(size_t)(n0 + n) * 256 + c]);
    }

    f32x4 acc[4][2] = {};
    for (int k0 = 0; k0 < 256; k0 += 64) {
        __syncthreads();   // covers Bs on first iter; As reuse on later iters
        #pragma unroll
        for (int it = 0; it < 4; ++it) {
            int f = t + 256 * it;
            int r = f >> 3, c = (f & 7) * 8;
            int row = m0 + r;
            uint4 v = make_uint4(0u, 0u, 0u, 0u);
            if (row < M) v = *reinterpret_cast<const uint4*>(&A[(size_t)row * 256 + k0 + c]);
            *reinterpret_cast<uint4*>(&As[r * LDA + c]) = v;
        }
        __syncthreads();
        #pragma unroll
        for (int kk = 0; kk < 64; kk += 32) {
            bf16x8 af[4], bfr[2];
            #pragma unroll
            for (int mi = 0; mi < 4; ++mi)
                af[mi] = *reinterpret_cast<const bf16x8*>(
                    &As[(wm * 64 + mi * 16 + l15) * LDA + kk + quad * 8]);
            #pragma unroll
            for (int ni = 0; ni < 2; ++ni)
                bfr[ni] = *reinterpret_cast<const bf16x8*>(
                    &Bs[(wn * 32 + ni * 16 + l15) * LDB + k0 + kk + quad * 8]);
            #pragma unroll
            for (int mi = 0; mi < 4; ++mi)
                #pragma unroll
                for (int ni = 0; ni < 2; ++ni)
                    acc[mi][ni] = __builtin_amdgcn_mfma_f32_16x16x32_bf16(
                        af[mi], bfr[ni], acc[mi][ni], 0, 0, 0);
        }
    }
    // epilogue: C/D layout col=lane&15, row=quad*4+reg
    #pragma unroll
    for (int mi = 0; mi < 4; ++mi) {
        #pragma unroll
        for (int ni = 0; ni < 2; ++ni) {
            #pragma unroll
            for (int r = 0; r < 4; ++r) {
                int row = m0 + wm * 64 + mi * 16 + quad * 4 + r;
                int col = n0 + wn * 32 + ni * 16 + l15;
                if (row < M)
                    C[(size_t)row * 256 + col] = __float2bfloat16(acc[mi][ni][r]);
            }
        }
    }
}

// ---------------- fp32 tiled GEMM (layer 2, K=64) ----------------
#define BM 64
#define BN 64
#define BK 32
#define LDP 68

__global__ __launch_bounds__(256) void k_gemm(const float* __restrict__ A,
                                              const float* __restrict__ B,
                                              float* __restrict__ C, int M, int K, int NC) {
    __shared__ float As[BK * LDP];
    __shared__ float Bs[BK * LDP];
    const int t = threadIdx.x;
    const int m0 = blockIdx.x * BM;
    const int n0 = blockIdx.y * BN;
    const int tx = t & 15, ty = t >> 4;
    float acc[4][4] = {};
    for (int k0 = 0; k0 < K; k0 += BK) {
        #pragma unroll
        for (int it = 0; it < 8; ++it) {
            int f = t + 256 * it;
            int r = f >> 5, c = f & 31;
            int row = m0 + r;
            float v = 0.f;
            if (row < M) v = A[(size_t)row * K + k0 + c];
            As[c * LDP + r] = v;
        }
        #pragma unroll
        for (int it = 0; it < 8; ++it) {
            int f = t + 256 * it;
            int kr = f >> 6, c = f & 63;
            Bs[kr * LDP + c] = B[(size_t)(k0 + kr) * NC + n0 + c];
        }
        __syncthreads();
        #pragma unroll
        for (int k = 0; k < BK; ++k) {
            const float4 av = *reinterpret_cast<const float4*>(&As[k * LDP + ty * 4]);
            const float4 bv = *reinterpret_cast<const float4*>(&Bs[k * LDP + tx * 4]);
            float ar[4] = {av.x, av.y, av.z, av.w};
            float br[4] = {bv.x, bv.y, bv.z, bv.w};
            #pragma unroll
            for (int mi = 0; mi < 4; ++mi)
                #pragma unroll
                for (int ni = 0; ni < 4; ++ni)
                    acc[mi][ni] = fmaf(ar[mi], br[ni], acc[mi][ni]);
        }
        __syncthreads();
    }
    #pragma unroll
    for (int mi = 0; mi < 4; ++mi) {
        int row = m0 + ty * 4 + mi;
        if (row < M) {
            float4 o = make_float4(acc[mi][0], acc[mi][1], acc[mi][2], acc[mi][3]);
            *reinterpret_cast<float4*>(&C[(size_t)row * NC + n0 + tx * 4]) = o;
        }
    }
}

// ---------------- layer 1 node kernel (bf16 xl/xr) ----------------
__global__ void k_node1(const __hip_bfloat16* __restrict__ xl,
                        const __hip_bfloat16* __restrict__ xr,
                        const int* __restrict__ rowstart, const int* __restrict__ csr_src,
                        const float* __restrict__ att,   // [4,64]
                        const float* __restrict__ bias,  // [64]
                        const float* __restrict__ lng,
                        const float* __restrict__ lnb,
                        float* __restrict__ hout) {
    int wid = (blockIdx.x * 256 + threadIdx.x) >> 6;
    int lane = threadIdx.x & 63;
    if (wid >= NNODES) return;
    const int i = wid;
    const int grp = lane >> 4;
    const int c0 = (lane & 15) * 4;
    const int fb = lane * 4;

    const float4 xrv = ldbf4(xr + (size_t)i * 256 + fb);
    const float4 av4 = *reinterpret_cast<const float4*>(att + fb);
    float a0 = av4.x, a1 = av4.y, a2 = av4.z, a3 = av4.w;

    float m = -1e30f, l = 0.f;
    float acc0 = 0.f, acc1 = 0.f, acc2 = 0.f, acc3 = 0.f;
    const int p1 = rowstart[i + 1];
    for (int p = rowstart[i]; p < p1; ++p) {
        int j = csr_src[p];
        const float4 xlv = ldbf4(xl + (size_t)j * 256 + fb);
        float t0 = lrelu(xlv.x + xrv.x);
        float t1 = lrelu(xlv.y + xrv.y);
        float t2 = lrelu(xlv.z + xrv.z);
        float t3 = lrelu(xlv.w + xrv.w);
        float e = t0 * a0 + t1 * a1 + t2 * a2 + t3 * a3;
        e += __shfl_xor(e, 1);
        e += __shfl_xor(e, 2);
        e += __shfl_xor(e, 4);
        e += __shfl_xor(e, 8);
        float mn = fmaxf(m, e);
        float sc = __expf(m - mn);
        float pe = __expf(e - mn);
        l = l * sc + pe;
        acc0 = acc0 * sc + pe * xlv.x;
        acc1 = acc1 * sc + pe * xlv.y;
        acc2 = acc2 * sc + pe * xlv.z;
        acc3 = acc3 * sc + pe * xlv.w;
        m = mn;
    }
    float inv = 1.f / (l + SM_EPS);
    float v0 = acc0 * inv, v1 = acc1 * inv, v2 = acc2 * inv, v3 = acc3 * inv;
    v0 += __shfl_xor(v0, 16); v0 += __shfl_xor(v0, 32);
    v1 += __shfl_xor(v1, 16); v1 += __shfl_xor(v1, 32);
    v2 += __shfl_xor(v2, 16); v2 += __shfl_xor(v2, 32);
    v3 += __shfl_xor(v3, 16); v3 += __shfl_xor(v3, 32);
    float o0 = v0 * 0.25f + bias[c0 + 0];
    float o1 = v1 * 0.25f + bias[c0 + 1];
    float o2 = v2 * 0.25f + bias[c0 + 2];
    float o3 = v3 * 0.25f + bias[c0 + 3];
    float s = o0 + o1 + o2 + o3;
    s += __shfl_xor(s, 1); s += __shfl_xor(s, 2); s += __shfl_xor(s, 4); s += __shfl_xor(s, 8);
    float mu = s * 0.015625f;
    float d0 = o0 - mu, d1 = o1 - mu, d2 = o2 - mu, d3 = o3 - mu;
    float ss = d0 * d0 + d1 * d1 + d2 * d2 + d3 * d3;
    ss += __shfl_xor(ss, 1); ss += __shfl_xor(ss, 2); ss += __shfl_xor(ss, 4); ss += __shfl_xor(ss, 8);
    float istd = rsqrtf(ss * 0.015625f + LN_EPS);
    float h0 = fmaxf(d0 * istd * lng[c0 + 0] + lnb[c0 + 0], 0.f);
    float h1v = fmaxf(d1 * istd * lng[c0 + 1] + lnb[c0 + 1], 0.f);
    float h2 = fmaxf(d2 * istd * lng[c0 + 2] + lnb[c0 + 2], 0.f);
    float h3 = fmaxf(d3 * istd * lng[c0 + 3] + lnb[c0 + 3], 0.f);
    if (grp == 0) {
        float4 o = make_float4(h0, h1v, h2, h3);
        *reinterpret_cast<float4*>(hout + (size_t)i * 64 + c0) = o;
    }
}

// ---------------- layer 2 node kernel (fp32) ----------------
__global__ void k_node2(const float* __restrict__ xl, const float* __restrict__ xr,
                        const int* __restrict__ rowstart, const int* __restrict__ csr_src,
                        const float* __restrict__ att,
                        const float* __restrict__ bias,
                        const float* __restrict__ lng,
                        const float* __restrict__ lnb,
                        float* __restrict__ out) {
    int wid = (blockIdx.x * 256 + threadIdx.x) >> 6;
    int lane = threadIdx.x & 63;
    if (wid >= NNODES) return;
    const int i = wid;
    float xrv = xr[(size_t)i * 64 + lane];
    float a = att[lane];
    float m = -1e30f, l = 0.f, acc = 0.f;
    const int p1 = rowstart[i + 1];
    for (int p = rowstart[i]; p < p1; ++p) {
        int j = csr_src[p];
        float xlv = xl[(size_t)j * 64 + lane];
        float e = lrelu(xlv + xrv) * a;
        e += __shfl_xor(e, 1); e += __shfl_xor(e, 2); e += __shfl_xor(e, 4);
        e += __shfl_xor(e, 8); e += __shfl_xor(e, 16); e += __shfl_xor(e, 32);
        float mn = fmaxf(m, e);
        float sc = __expf(m - mn);
        float pe = __expf(e - mn);
        l = l * sc + pe;
        acc = acc * sc + pe * xlv;
        m = mn;
    }
    float v = acc / (l + SM_EPS) + bias[lane];
    float s = v;
    s += __shfl_xor(s, 1); s += __shfl_xor(s, 2); s += __shfl_xor(s, 4);
    s += __shfl_xor(s, 8); s += __shfl_xor(s, 16); s += __shfl_xor(s, 32);
    float mu = s * 0.015625f;
    float d = v - mu;
    float ss = d * d;
    ss += __shfl_xor(ss, 1); ss += __shfl_xor(ss, 2); ss += __shfl_xor(ss, 4);
    ss += __shfl_xor(ss, 8); ss += __shfl_xor(ss, 16); ss += __shfl_xor(ss, 32);
    float istd = rsqrtf(ss * 0.015625f + LN_EPS);
    float y = d * istd * lng[lane] + lnb[lane];
    out[(size_t)i * 64 + lane] = y;
}

extern "C" void kernel_launch(void* const* d_in, const int* in_sizes, int n_in,
                              void* d_out, int out_size, void* d_ws, size_t ws_size,
                              hipStream_t stream) {
    const float* x    = (const float*)d_in[0];
    const int*   ei   = (const int*)d_in[1];
    const float* W1l  = (const float*)d_in[2];
    const float* W1r  = (const float*)d_in[3];
    const float* att1 = (const float*)d_in[4];
    const float* b1   = (const float*)d_in[5];
    const float* ln1g = (const float*)d_in[6];
    const float* ln1b = (const float*)d_in[7];
    const float* W2l  = (const float*)d_in[8];
    const float* W2r  = (const float*)d_in[9];
    const float* att2 = (const float*)d_in[10];
    const float* b2   = (const float*)d_in[11];
    const float* ln2g = (const float*)d_in[12];
    const float* ln2b = (const float*)d_in[13];
    float* out = (float*)d_out;

    char* w = (char*)d_ws;
    size_t off = 0;
    auto alloc = [&](size_t bytes) -> void* {
        void* p = w + off;
        off += (bytes + 255) & ~(size_t)255;
        return p;
    };
    __hip_bfloat16* xb    = (__hip_bfloat16*)alloc((size_t)NNODES * 256 * 2); // dead after MFMA gemms
    __hip_bfloat16* xl1   = (__hip_bfloat16*)alloc((size_t)NNODES * 256 * 2);
    __hip_bfloat16* xr1   = (__hip_bfloat16*)alloc((size_t)NNODES * 256 * 2);
    __hip_bfloat16* w1lT  = (__hip_bfloat16*)alloc(256 * 256 * 2);
    __hip_bfloat16* w1rT  = (__hip_bfloat16*)alloc(256 * 256 * 2);
    float* h1      = (float*)alloc((size_t)NNODES * 64 * 4);
    int* deg       = (int*)alloc((size_t)NNODES * 4);
    int* rowstart  = (int*)alloc((size_t)(NNODES + 1) * 4);
    int* cursor    = (int*)alloc((size_t)NNODES * 4);
    int* csr_src   = (int*)alloc((size_t)ETOT * 4);
    int* blocksum  = (int*)alloc(1024);
    // layer-2 activations alias the (dead) xb region: 2 x 12.8 MB = 25.6 MB = sizeof(xb)
    float* xl2 = (float*)xb;
    float* xr2 = xl2 + (size_t)NNODES * 64;
    (void)ws_size; (void)in_sizes; (void)n_in; (void)out_size;

    hipMemsetAsync(deg, 0, (size_t)NNODES * 4, stream);
    const int histB = (ETOT + 255) / 256;
    const int scanB = (NNODES + 255) / 256;
    k_hist<<<histB, 256, 0, stream>>>(ei, deg);
    k_scan1<<<scanB, 256, 0, stream>>>(deg, rowstart, blocksum);
    k_scan2<<<1, 256, 0, stream>>>(blocksum, scanB);
    k_scan3<<<scanB, 256, 0, stream>>>(rowstart, blocksum, cursor);
    k_scatter<<<histB, 256, 0, stream>>>(ei, cursor, csr_src);

    k_cast_x<<<(NNODES * 256 / 4 + 255) / 256, 256, 0, stream>>>(x, xb, NNODES * 256 / 4);
    k_cast_wT<<<256, 256, 0, stream>>>(W1l, w1lT);
    k_cast_wT<<<256, 256, 0, stream>>>(W1r, w1rT);

    dim3 gm((NNODES + GBM - 1) / GBM, 256 / GBN);   // (391, 4)
    k_gemm_mfma<<<gm, 256, 0, stream>>>(xb, w1lT, xl1, NNODES);
    k_gemm_mfma<<<gm, 256, 0, stream>>>(xb, w1rT, xr1, NNODES);
    k_node1<<<(NNODES + 3) / 4, 256, 0, stream>>>(xl1, xr1, rowstart, csr_src,
                                                  att1, b1, ln1g, ln1b, h1);
    dim3 g2((NNODES + BM - 1) / BM, 1);
    k_gemm<<<g2, 256, 0, stream>>>(h1, W2l, xl2, NNODES, 64, 64);
    k_gemm<<<g2, 256, 0, stream>>>(h1, W2r, xr2, NNODES, 64, 64);
    k_node2<<<(NNODES + 3) / 4, 256, 0, stream>>>(xl2, xr2, rowstart, csr_src,
                                                  att2, b2, ln2g, ln2b, out);
}

// Round 4
// 493.772 us; speedup vs baseline: 1.3887x; 1.0735x over previous
//
#include <hip/hip_runtime.h>
#include <hip/hip_bf16.h>

#define NNODES 50000
#define NEDGES 800000
#define ETOT   850000
#define NEG_SLOPE 0.2f
#define LN_EPS 1e-5f
#define SM_EPS 1e-16f

typedef short bf16x8 __attribute__((ext_vector_type(8)));
typedef float f32x4  __attribute__((ext_vector_type(4)));

__device__ __forceinline__ float lrelu(float x) { return x > 0.f ? x : NEG_SLOPE * x; }

__device__ __forceinline__ float4 ldbf4(const __hip_bfloat16* p) {
    uint2 raw = *reinterpret_cast<const uint2*>(p);
    __hip_bfloat162 ab = *reinterpret_cast<__hip_bfloat162*>(&raw.x);
    __hip_bfloat162 cd = *reinterpret_cast<__hip_bfloat162*>(&raw.y);
    float2 f0 = __bfloat1622float2(ab);
    float2 f1 = __bfloat1622float2(cd);
    return make_float4(f0.x, f0.y, f1.x, f1.y);
}

__device__ __forceinline__ unsigned pack_bf2(float a, float b) {
    __hip_bfloat162 p;
    p.x = __float2bfloat16(a);
    p.y = __float2bfloat16(b);
    return *reinterpret_cast<unsigned*>(&p);
}

// ---------------- combined weight transpose+cast ----------------
// W[k][n] fp32 -> WT[n][k] bf16 for all four weight matrices
__global__ void k_cast_w(const float* __restrict__ W1l, const float* __restrict__ W1r,
                         const float* __restrict__ W2l, const float* __restrict__ W2r,
                         __hip_bfloat16* __restrict__ w1lT, __hip_bfloat16* __restrict__ w1rT,
                         __hip_bfloat16* __restrict__ w2lT, __hip_bfloat16* __restrict__ w2rT) {
    int t = blockIdx.x * 256 + threadIdx.x;
    if (t < 65536) {
        int k = t >> 8, n = t & 255;
        w1lT[n * 256 + k] = __float2bfloat16(W1l[t]);
    } else if (t < 131072) {
        int u = t - 65536; int k = u >> 8, n = u & 255;
        w1rT[n * 256 + k] = __float2bfloat16(W1r[u]);
    } else if (t < 135168) {
        int u = t - 131072; int k = u >> 6, n = u & 63;
        w2lT[n * 64 + k] = __float2bfloat16(W2l[u]);
    } else if (t < 139264) {
        int u = t - 135168; int k = u >> 6, n = u & 63;
        w2rT[n * 64 + k] = __float2bfloat16(W2r[u]);
    }
}

// ---------------- CSR build ----------------
__global__ void k_hist(const int* __restrict__ ei, int* __restrict__ deg) {
    int e = blockIdx.x * 256 + threadIdx.x;
    if (e >= ETOT) return;
    int dst = (e < NEDGES) ? ei[NEDGES + e] : (e - NEDGES);
    atomicAdd(&deg[dst], 1);
}

__global__ void k_scan1(const int* __restrict__ deg, int* __restrict__ rowstart,
                        int* __restrict__ blocksum) {
    __shared__ int s[256];
    int t = threadIdx.x;
    int i = blockIdx.x * 256 + t;
    int v = (i < NNODES) ? deg[i] : 0;
    s[t] = v;
    __syncthreads();
    #pragma unroll
    for (int off = 1; off < 256; off <<= 1) {
        int add = (t >= off) ? s[t - off] : 0;
        __syncthreads();
        s[t] += add;
        __syncthreads();
    }
    if (i < NNODES) rowstart[i] = s[t] - v;
    if (t == 255) blocksum[blockIdx.x] = s[255];
}

__global__ void k_scan2(int* __restrict__ bs, int nb) {
    __shared__ int s[256];
    int t = threadIdx.x;
    int v = (t < nb) ? bs[t] : 0;
    s[t] = v;
    __syncthreads();
    #pragma unroll
    for (int off = 1; off < 256; off <<= 1) {
        int add = (t >= off) ? s[t - off] : 0;
        __syncthreads();
        s[t] += add;
        __syncthreads();
    }
    if (t < nb) bs[t] = s[t] - v;
}

__global__ void k_scan3(int* __restrict__ rowstart, const int* __restrict__ boff,
                        int* __restrict__ cursor) {
    int i = blockIdx.x * 256 + threadIdx.x;
    if (i < NNODES) {
        int r = rowstart[i] + boff[i >> 8];
        rowstart[i] = r;
        cursor[i] = r;
    } else if (i == NNODES) {
        rowstart[NNODES] = ETOT;
    }
}

__global__ void k_scatter(const int* __restrict__ ei, int* __restrict__ cursor,
                          int* __restrict__ csr_src) {
    int e = blockIdx.x * 256 + threadIdx.x;
    if (e >= ETOT) return;
    int src, dst;
    if (e < NEDGES) { src = ei[e]; dst = ei[NEDGES + e]; }
    else { src = e - NEDGES; dst = src; }
    int pos = atomicAdd(&cursor[dst], 1);
    csr_src[pos] = src;
}

// ---------------- MFMA bf16 GEMM: C[M,NC] = A[M,KDIM] @ WT^T, out bf16 ----------------
// WT is [NC n][KDIM k]. Tile 128 x 64, 4 waves. AT=float => cast fused in staging.
#define GBM 128
#define GBN 64
#define LDA 72

template <int KDIM, int NC, typename AT>
__global__ __launch_bounds__(256) void k_gemm_mfma(
    const AT* __restrict__ A,
    const __hip_bfloat16* __restrict__ WT,
    __hip_bfloat16* __restrict__ C, int M)
{
    constexpr int LDB = KDIM + 8;
    __shared__ short As[GBM * LDA];
    __shared__ short Bs[GBN * LDB];
    const int t = threadIdx.x;
    const int m0 = blockIdx.x * GBM;
    const int n0 = blockIdx.y * GBN;
    const int wave = t >> 6, lane = t & 63;
    const int wm = wave & 1, wn = wave >> 1;
    const int l15 = lane & 15, quad = lane >> 4;

    // stage full B panel once: rows n0..n0+63, all K
    constexpr int K8 = KDIM / 8;
    #pragma unroll
    for (int it = 0; it < (GBN * K8) / 256; ++it) {
        int f = t + 256 * it;
        int n = f / K8, c = (f % K8) * 8;
        *reinterpret_cast<uint4*>(&Bs[n * LDB + c]) =
            *reinterpret_cast<const uint4*>(&WT[(size_t)(n0 + n) * KDIM + c]);
    }

    f32x4 acc[4][2] = {};
    for (int k0 = 0; k0 < KDIM; k0 += 64) {
        __syncthreads();   // covers Bs on first iter; As reuse afterwards
        if constexpr (sizeof(AT) == 4) {   // fp32 A: fused cast
            #pragma unroll
            for (int it = 0; it < 8; ++it) {
                int f = t + 256 * it;
                int r = f >> 4, c = (f & 15) * 4;
                int row = m0 + r;
                float4 v = make_float4(0.f, 0.f, 0.f, 0.f);
                if (row < M) v = *reinterpret_cast<const float4*>(&A[(size_t)row * KDIM + k0 + c]);
                uint2 pk;
                pk.x = pack_bf2(v.x, v.y);
                pk.y = pack_bf2(v.z, v.w);
                *reinterpret_cast<uint2*>(&As[r * LDA + c]) = pk;
            }
        } else {                           // bf16 A
            #pragma unroll
            for (int it = 0; it < 4; ++it) {
                int f = t + 256 * it;
                int r = f >> 3, c = (f & 7) * 8;
                int row = m0 + r;
                uint4 v = make_uint4(0u, 0u, 0u, 0u);
                if (row < M) v = *reinterpret_cast<const uint4*>(&A[(size_t)row * KDIM + k0 + c]);
                *reinterpret_cast<uint4*>(&As[r * LDA + c]) = v;
            }
        }
        __syncthreads();
        #pragma unroll
        for (int kk = 0; kk < 64; kk += 32) {
            bf16x8 af[4], bfr[2];
            #pragma unroll
            for (int mi = 0; mi < 4; ++mi)
                af[mi] = *reinterpret_cast<const bf16x8*>(
                    &As[(wm * 64 + mi * 16 + l15) * LDA + kk + quad * 8]);
            #pragma unroll
            for (int ni = 0; ni < 2; ++ni)
                bfr[ni] = *reinterpret_cast<const bf16x8*>(
                    &Bs[(wn * 32 + ni * 16 + l15) * LDB + k0 + kk + quad * 8]);
            #pragma unroll
            for (int mi = 0; mi < 4; ++mi)
                #pragma unroll
                for (int ni = 0; ni < 2; ++ni)
                    acc[mi][ni] = __builtin_amdgcn_mfma_f32_16x16x32_bf16(
                        af[mi], bfr[ni], acc[mi][ni], 0, 0, 0);
        }
    }
    #pragma unroll
    for (int mi = 0; mi < 4; ++mi)
        #pragma unroll
        for (int ni = 0; ni < 2; ++ni)
            #pragma unroll
            for (int r = 0; r < 4; ++r) {
                int row = m0 + wm * 64 + mi * 16 + quad * 4 + r;
                int col = n0 + wn * 32 + ni * 16 + l15;
                if (row < M)
                    C[(size_t)row * NC + col] = __float2bfloat16(acc[mi][ni][r]);
            }
}

// ---------------- layer 1 node kernel: 4 edges/wave, 16-lane group per edge ----------------
// group g handles edge p+g; lane k15 holds channels k15*4..+3 of each of 4 heads
__global__ void k_node1(const __hip_bfloat16* __restrict__ xl,
                        const __hip_bfloat16* __restrict__ xr,
                        const int* __restrict__ rowstart, const int* __restrict__ csr_src,
                        const float* __restrict__ att,   // [4,64]
                        const float* __restrict__ bias,  // [64]
                        const float* __restrict__ lng,
                        const float* __restrict__ lnb,
                        __hip_bfloat16* __restrict__ h1b) {
    int wid = (blockIdx.x * 256 + threadIdx.x) >> 6;
    int lane = threadIdx.x & 63;
    if (wid >= NNODES) return;
    const int i = wid;
    const int grp = lane >> 4;
    const int k15 = lane & 15;
    const int c0 = k15 * 4;

    float4 xrv[4], av[4];
    #pragma unroll
    for (int h = 0; h < 4; ++h) {
        xrv[h] = ldbf4(xr + (size_t)i * 256 + h * 64 + c0);
        av[h]  = *reinterpret_cast<const float4*>(att + h * 64 + c0);
    }
    float m[4], l[4];
    float4 acc[4];
    #pragma unroll
    for (int h = 0; h < 4; ++h) {
        m[h] = -1e30f; l[h] = 0.f; acc[h] = make_float4(0.f, 0.f, 0.f, 0.f);
    }

    const int p0 = rowstart[i], p1 = rowstart[i + 1];
    for (int p = p0; p < p1; p += 4) {
        int pe = p + grp;
        bool valid = pe < p1;
        int j = csr_src[valid ? pe : p1 - 1];
        float4 xlv[4];
        float eh[4];
        #pragma unroll
        for (int h = 0; h < 4; ++h) {
            xlv[h] = ldbf4(xl + (size_t)j * 256 + h * 64 + c0);
            float t0 = lrelu(xlv[h].x + xrv[h].x);
            float t1 = lrelu(xlv[h].y + xrv[h].y);
            float t2 = lrelu(xlv[h].z + xrv[h].z);
            float t3 = lrelu(xlv[h].w + xrv[h].w);
            eh[h] = t0 * av[h].x + t1 * av[h].y + t2 * av[h].z + t3 * av[h].w;
        }
        #pragma unroll
        for (int s = 1; s <= 8; s <<= 1) {
            #pragma unroll
            for (int h = 0; h < 4; ++h) eh[h] += __shfl_xor(eh[h], s);
        }
        #pragma unroll
        for (int h = 0; h < 4; ++h) {
            float mn = fmaxf(m[h], eh[h]);
            float sc = __expf(m[h] - mn);
            float pw = __expf(eh[h] - mn);
            sc = valid ? sc : 1.f;
            pw = valid ? pw : 0.f;
            mn = valid ? mn : m[h];
            l[h] = l[h] * sc + pw;
            acc[h].x = acc[h].x * sc + pw * xlv[h].x;
            acc[h].y = acc[h].y * sc + pw * xlv[h].y;
            acc[h].z = acc[h].z * sc + pw * xlv[h].z;
            acc[h].w = acc[h].w * sc + pw * xlv[h].w;
            m[h] = mn;
        }
    }
    // merge the 4 group-states (flash-style combine)
    #pragma unroll
    for (int s = 16; s <= 32; s <<= 1) {
        #pragma unroll
        for (int h = 0; h < 4; ++h) {
            float mo = __shfl_xor(m[h], s);
            float lo = __shfl_xor(l[h], s);
            float ax = __shfl_xor(acc[h].x, s);
            float ay = __shfl_xor(acc[h].y, s);
            float az = __shfl_xor(acc[h].z, s);
            float aw = __shfl_xor(acc[h].w, s);
            float mn = fmaxf(m[h], mo);
            float sa = __expf(m[h] - mn);
            float sb = __expf(mo - mn);
            l[h] = l[h] * sa + lo * sb;
            acc[h].x = acc[h].x * sa + ax * sb;
            acc[h].y = acc[h].y * sa + ay * sb;
            acc[h].z = acc[h].z * sa + az * sb;
            acc[h].w = acc[h].w * sa + aw * sb;
            m[h] = mn;
        }
    }
    float i0 = 1.f / (l[0] + SM_EPS), i1 = 1.f / (l[1] + SM_EPS);
    float i2 = 1.f / (l[2] + SM_EPS), i3 = 1.f / (l[3] + SM_EPS);
    const float4 bv = *reinterpret_cast<const float4*>(bias + c0);
    float o0 = (acc[0].x * i0 + acc[1].x * i1 + acc[2].x * i2 + acc[3].x * i3) * 0.25f + bv.x;
    float o1 = (acc[0].y * i0 + acc[1].y * i1 + acc[2].y * i2 + acc[3].y * i3) * 0.25f + bv.y;
    float o2 = (acc[0].z * i0 + acc[1].z * i1 + acc[2].z * i2 + acc[3].z * i3) * 0.25f + bv.z;
    float o3 = (acc[0].w * i0 + acc[1].w * i1 + acc[2].w * i2 + acc[3].w * i3) * 0.25f + bv.w;
    // LN over 64 ch within the 16-lane group
    float s1 = o0 + o1 + o2 + o3;
    s1 += __shfl_xor(s1, 1); s1 += __shfl_xor(s1, 2); s1 += __shfl_xor(s1, 4); s1 += __shfl_xor(s1, 8);
    float mu = s1 * 0.015625f;
    float d0 = o0 - mu, d1 = o1 - mu, d2 = o2 - mu, d3 = o3 - mu;
    float s2 = d0 * d0 + d1 * d1 + d2 * d2 + d3 * d3;
    s2 += __shfl_xor(s2, 1); s2 += __shfl_xor(s2, 2); s2 += __shfl_xor(s2, 4); s2 += __shfl_xor(s2, 8);
    float istd = rsqrtf(s2 * 0.015625f + LN_EPS);
    const float4 gv = *reinterpret_cast<const float4*>(lng + c0);
    const float4 bb = *reinterpret_cast<const float4*>(lnb + c0);
    float h0 = fmaxf(d0 * istd * gv.x + bb.x, 0.f);
    float h1 = fmaxf(d1 * istd * gv.y + bb.y, 0.f);
    float h2 = fmaxf(d2 * istd * gv.z + bb.z, 0.f);
    float h3 = fmaxf(d3 * istd * gv.w + bb.w, 0.f);
    if (grp == 0) {
        uint2 pk;
        pk.x = pack_bf2(h0, h1);
        pk.y = pack_bf2(h2, h3);
        *reinterpret_cast<uint2*>(h1b + (size_t)i * 64 + c0) = pk;
    }
}

// ---------------- layer 2 node kernel: 4 edges/wave, final LN, fp32 out ----------------
__global__ void k_node2(const __hip_bfloat16* __restrict__ xl,
                        const __hip_bfloat16* __restrict__ xr,
                        const int* __restrict__ rowstart, const int* __restrict__ csr_src,
                        const float* __restrict__ att,   // [64]
                        const float* __restrict__ bias,
                        const float* __restrict__ lng,
                        const float* __restrict__ lnb,
                        float* __restrict__ out) {
    int wid = (blockIdx.x * 256 + threadIdx.x) >> 6;
    int lane = threadIdx.x & 63;
    if (wid >= NNODES) return;
    const int i = wid;
    const int grp = lane >> 4;
    const int k15 = lane & 15;
    const int c0 = k15 * 4;

    const float4 xrv = ldbf4(xr + (size_t)i * 64 + c0);
    const float4 av  = *reinterpret_cast<const float4*>(att + c0);
    float m = -1e30f, l = 0.f;
    float4 acc = make_float4(0.f, 0.f, 0.f, 0.f);

    const int p0 = rowstart[i], p1 = rowstart[i + 1];
    for (int p = p0; p < p1; p += 4) {
        int pe = p + grp;
        bool valid = pe < p1;
        int j = csr_src[valid ? pe : p1 - 1];
        float4 xlv = ldbf4(xl + (size_t)j * 64 + c0);
        float e = lrelu(xlv.x + xrv.x) * av.x + lrelu(xlv.y + xrv.y) * av.y
                + lrelu(xlv.z + xrv.z) * av.z + lrelu(xlv.w + xrv.w) * av.w;
        e += __shfl_xor(e, 1); e += __shfl_xor(e, 2); e += __shfl_xor(e, 4); e += __shfl_xor(e, 8);
        float mn = fmaxf(m, e);
        float sc = __expf(m - mn);
        float pw = __expf(e - mn);
        sc = valid ? sc : 1.f;
        pw = valid ? pw : 0.f;
        mn = valid ? mn : m;
        l = l * sc + pw;
        acc.x = acc.x * sc + pw * xlv.x;
        acc.y = acc.y * sc + pw * xlv.y;
        acc.z = acc.z * sc + pw * xlv.z;
        acc.w = acc.w * sc + pw * xlv.w;
        m = mn;
    }
    #pragma unroll
    for (int s = 16; s <= 32; s <<= 1) {
        float mo = __shfl_xor(m, s);
        float lo = __shfl_xor(l, s);
        float ax = __shfl_xor(acc.x, s);
        float ay = __shfl_xor(acc.y, s);
        float az = __shfl_xor(acc.z, s);
        float aw = __shfl_xor(acc.w, s);
        float mn = fmaxf(m, mo);
        float sa = __expf(m - mn);
        float sb = __expf(mo - mn);
        l = l * sa + lo * sb;
        acc.x = acc.x * sa + ax * sb;
        acc.y = acc.y * sa + ay * sb;
        acc.z = acc.z * sa + az * sb;
        acc.w = acc.w * sa + aw * sb;
        m = mn;
    }
    float inv = 1.f / (l + SM_EPS);
    const float4 bv = *reinterpret_cast<const float4*>(bias + c0);
    float o0 = acc.x * inv + bv.x;
    float o1 = acc.y * inv + bv.y;
    float o2 = acc.z * inv + bv.z;
    float o3 = acc.w * inv + bv.w;
    float s1 = o0 + o1 + o2 + o3;
    s1 += __shfl_xor(s1, 1); s1 += __shfl_xor(s1, 2); s1 += __shfl_xor(s1, 4); s1 += __shfl_xor(s1, 8);
    float mu = s1 * 0.015625f;
    float d0 = o0 - mu, d1 = o1 - mu, d2 = o2 - mu, d3 = o3 - mu;
    float s2 = d0 * d0 + d1 * d1 + d2 * d2 + d3 * d3;
    s2 += __shfl_xor(s2, 1); s2 += __shfl_xor(s2, 2); s2 += __shfl_xor(s2, 4); s2 += __shfl_xor(s2, 8);
    float istd = rsqrtf(s2 * 0.015625f + LN_EPS);
    const float4 gv = *reinterpret_cast<const float4*>(lng + c0);
    const float4 bb = *reinterpret_cast<const float4*>(lnb + c0);
    if (grp == 0) {
        float4 y;
        y.x = d0 * istd * gv.x + bb.x;
        y.y = d1 * istd * gv.y + bb.y;
        y.z = d2 * istd * gv.z + bb.z;
        y.w = d3 * istd * gv.w + bb.w;
        *reinterpret_cast<float4*>(out + (size_t)i * 64 + c0) = y;
    }
}

extern "C" void kernel_launch(void* const* d_in, const int* in_sizes, int n_in,
                              void* d_out, int out_size, void* d_ws, size_t ws_size,
                              hipStream_t stream) {
    const float* x    = (const float*)d_in[0];
    const int*   ei   = (const int*)d_in[1];
    const float* W1l  = (const float*)d_in[2];
    const float* W1r  = (const float*)d_in[3];
    const float* att1 = (const float*)d_in[4];
    const float* b1   = (const float*)d_in[5];
    const float* ln1g = (const float*)d_in[6];
    const float* ln1b = (const float*)d_in[7];
    const float* W2l  = (const float*)d_in[8];
    const float* W2r  = (const float*)d_in[9];
    const float* att2 = (const float*)d_in[10];
    const float* b2   = (const float*)d_in[11];
    const float* ln2g = (const float*)d_in[12];
    const float* ln2b = (const float*)d_in[13];
    float* out = (float*)d_out;

    char* w = (char*)d_ws;
    size_t off = 0;
    auto alloc = [&](size_t bytes) -> void* {
        void* p = w + off;
        off += (bytes + 255) & ~(size_t)255;
        return p;
    };
    __hip_bfloat16* xl1  = (__hip_bfloat16*)alloc((size_t)NNODES * 256 * 2);
    __hip_bfloat16* xr1  = (__hip_bfloat16*)alloc((size_t)NNODES * 256 * 2);
    __hip_bfloat16* h1b  = (__hip_bfloat16*)alloc((size_t)NNODES * 64 * 2);
    __hip_bfloat16* xl2  = (__hip_bfloat16*)alloc((size_t)NNODES * 64 * 2);
    __hip_bfloat16* xr2  = (__hip_bfloat16*)alloc((size_t)NNODES * 64 * 2);
    __hip_bfloat16* w1lT = (__hip_bfloat16*)alloc(256 * 256 * 2);
    __hip_bfloat16* w1rT = (__hip_bfloat16*)alloc(256 * 256 * 2);
    __hip_bfloat16* w2lT = (__hip_bfloat16*)alloc(64 * 64 * 2);
    __hip_bfloat16* w2rT = (__hip_bfloat16*)alloc(64 * 64 * 2);
    int* deg      = (int*)alloc((size_t)NNODES * 4);
    int* rowstart = (int*)alloc((size_t)(NNODES + 1) * 4);
    int* cursor   = (int*)alloc((size_t)NNODES * 4);
    int* csr_src  = (int*)alloc((size_t)ETOT * 4);
    int* blocksum = (int*)alloc(1024);
    (void)ws_size; (void)in_sizes; (void)n_in; (void)out_size;

    hipMemsetAsync(deg, 0, (size_t)NNODES * 4, stream);
    const int histB = (ETOT + 255) / 256;
    const int scanB = (NNODES + 255) / 256;
    k_hist<<<histB, 256, 0, stream>>>(ei, deg);
    k_scan1<<<scanB, 256, 0, stream>>>(deg, rowstart, blocksum);
    k_scan2<<<1, 256, 0, stream>>>(blocksum, scanB);
    k_scan3<<<scanB, 256, 0, stream>>>(rowstart, blocksum, cursor);
    k_scatter<<<histB, 256, 0, stream>>>(ei, cursor, csr_src);

    k_cast_w<<<544, 256, 0, stream>>>(W1l, W1r, W2l, W2r, w1lT, w1rT, w2lT, w2rT);

    dim3 gm1((NNODES + GBM - 1) / GBM, 256 / GBN);   // (391, 4)
    k_gemm_mfma<256, 256, float><<<gm1, 256, 0, stream>>>(x, w1lT, xl1, NNODES);
    k_gemm_mfma<256, 256, float><<<gm1, 256, 0, stream>>>(x, w1rT, xr1, NNODES);
    k_node1<<<(NNODES + 3) / 4, 256, 0, stream>>>(xl1, xr1, rowstart, csr_src,
                                                  att1, b1, ln1g, ln1b, h1b);
    dim3 gm2((NNODES + GBM - 1) / GBM, 1);           // (391, 1)
    k_gemm_mfma<64, 64, __hip_bfloat16><<<gm2, 256, 0, stream>>>(h1b, w2lT, xl2, NNODES);
    k_gemm_mfma<64, 64, __hip_bfloat16><<<gm2, 256, 0, stream>>>(h1b, w2rT, xr2, NNODES);
    k_node2<<<(NNODES + 3) / 4, 256, 0, stream>>>(xl2, xr2, rowstart, csr_src,
                                                  att2, b2, ln2g, ln2b, out);
}

// Round 5
// 470.344 us; speedup vs baseline: 1.4578x; 1.0498x over previous
//
#include <hip/hip_runtime.h>
#include <hip/hip_bf16.h>

#define NNODES 50000
#define NEDGES 800000
#define ETOT   850000
#define NEG_SLOPE 0.2f
#define LN_EPS 1e-5f
#define SM_EPS 1e-16f

typedef short bf16x8 __attribute__((ext_vector_type(8)));
typedef float f32x4  __attribute__((ext_vector_type(4)));

// lrelu(x) = max(x, 0.2x)  (valid for all x since 0.2x >= x iff x <= 0)
__device__ __forceinline__ float lrelu(float x) { return fmaxf(x, NEG_SLOPE * x); }

__device__ __forceinline__ float4 ldbf4(const __hip_bfloat16* p) {
    uint2 raw = *reinterpret_cast<const uint2*>(p);
    __hip_bfloat162 ab = *reinterpret_cast<__hip_bfloat162*>(&raw.x);
    __hip_bfloat162 cd = *reinterpret_cast<__hip_bfloat162*>(&raw.y);
    float2 f0 = __bfloat1622float2(ab);
    float2 f1 = __bfloat1622float2(cd);
    return make_float4(f0.x, f0.y, f1.x, f1.y);
}

__device__ __forceinline__ unsigned pack_bf2(float a, float b) {
    __hip_bfloat162 p;
    p.x = __float2bfloat16(a);
    p.y = __float2bfloat16(b);
    return *reinterpret_cast<unsigned*>(&p);
}

// edge logit partial: sum lrelu(x+xr)*a over this lane's 4 channels
__device__ __forceinline__ float edot(const float4& x, const float4& xr, const float4& a) {
    float t0 = lrelu(x.x + xr.x);
    float t1 = lrelu(x.y + xr.y);
    float t2 = lrelu(x.z + xr.z);
    float t3 = lrelu(x.w + xr.w);
    return t0 * a.x + t1 * a.y + t2 * a.z + t3 * a.w;
}

// ---------------- combined weight transpose+cast ----------------
__global__ void k_cast_w(const float* __restrict__ W1l, const float* __restrict__ W1r,
                         const float* __restrict__ W2l, const float* __restrict__ W2r,
                         __hip_bfloat16* __restrict__ w1lT, __hip_bfloat16* __restrict__ w1rT,
                         __hip_bfloat16* __restrict__ w2lT, __hip_bfloat16* __restrict__ w2rT) {
    int t = blockIdx.x * 256 + threadIdx.x;
    if (t < 65536) {
        int k = t >> 8, n = t & 255;
        w1lT[n * 256 + k] = __float2bfloat16(W1l[t]);
    } else if (t < 131072) {
        int u = t - 65536; int k = u >> 8, n = u & 255;
        w1rT[n * 256 + k] = __float2bfloat16(W1r[u]);
    } else if (t < 135168) {
        int u = t - 131072; int k = u >> 6, n = u & 63;
        w2lT[n * 64 + k] = __float2bfloat16(W2l[u]);
    } else if (t < 139264) {
        int u = t - 135168; int k = u >> 6, n = u & 63;
        w2rT[n * 64 + k] = __float2bfloat16(W2r[u]);
    }
}

// ---------------- CSR build ----------------
__global__ void k_hist(const int* __restrict__ ei, int* __restrict__ deg) {
    int e = blockIdx.x * 256 + threadIdx.x;
    if (e >= ETOT) return;
    int dst = (e < NEDGES) ? ei[NEDGES + e] : (e - NEDGES);
    atomicAdd(&deg[dst], 1);
}

__global__ void k_scan1(const int* __restrict__ deg, int* __restrict__ rowstart,
                        int* __restrict__ blocksum) {
    __shared__ int s[256];
    int t = threadIdx.x;
    int i = blockIdx.x * 256 + t;
    int v = (i < NNODES) ? deg[i] : 0;
    s[t] = v;
    __syncthreads();
    #pragma unroll
    for (int off = 1; off < 256; off <<= 1) {
        int add = (t >= off) ? s[t - off] : 0;
        __syncthreads();
        s[t] += add;
        __syncthreads();
    }
    if (i < NNODES) rowstart[i] = s[t] - v;
    if (t == 255) blocksum[blockIdx.x] = s[255];
}

__global__ void k_scan2(int* __restrict__ bs, int nb) {
    __shared__ int s[256];
    int t = threadIdx.x;
    int v = (t < nb) ? bs[t] : 0;
    s[t] = v;
    __syncthreads();
    #pragma unroll
    for (int off = 1; off < 256; off <<= 1) {
        int add = (t >= off) ? s[t - off] : 0;
        __syncthreads();
        s[t] += add;
        __syncthreads();
    }
    if (t < nb) bs[t] = s[t] - v;
}

__global__ void k_scan3(int* __restrict__ rowstart, const int* __restrict__ boff,
                        int* __restrict__ cursor) {
    int i = blockIdx.x * 256 + threadIdx.x;
    if (i < NNODES) {
        int r = rowstart[i] + boff[i >> 8];
        rowstart[i] = r;
        cursor[i] = r;
    } else if (i == NNODES) {
        rowstart[NNODES] = ETOT;
    }
}

__global__ void k_scatter(const int* __restrict__ ei, int* __restrict__ cursor,
                          int* __restrict__ csr_src) {
    int e = blockIdx.x * 256 + threadIdx.x;
    if (e >= ETOT) return;
    int src, dst;
    if (e < NEDGES) { src = ei[e]; dst = ei[NEDGES + e]; }
    else { src = e - NEDGES; dst = src; }
    int pos = atomicAdd(&cursor[dst], 1);
    csr_src[pos] = src;
}

// ---------------- MFMA bf16 GEMM: C[M,NC] = A[M,KDIM] @ WT^T, out bf16 ----------------
#define GBM 128
#define GBN 64
#define LDA 72

template <int KDIM, int NC, typename AT>
__global__ __launch_bounds__(256) void k_gemm_mfma(
    const AT* __restrict__ A,
    const __hip_bfloat16* __restrict__ WT,
    __hip_bfloat16* __restrict__ C, int M)
{
    constexpr int LDB = KDIM + 8;
    __shared__ short As[GBM * LDA];
    __shared__ short Bs[GBN * LDB];
    const int t = threadIdx.x;
    const int m0 = blockIdx.x * GBM;
    const int n0 = blockIdx.y * GBN;
    const int wave = t >> 6, lane = t & 63;
    const int wm = wave & 1, wn = wave >> 1;
    const int l15 = lane & 15, quad = lane >> 4;

    constexpr int K8 = KDIM / 8;
    #pragma unroll
    for (int it = 0; it < (GBN * K8) / 256; ++it) {
        int f = t + 256 * it;
        int n = f / K8, c = (f % K8) * 8;
        *reinterpret_cast<uint4*>(&Bs[n * LDB + c]) =
            *reinterpret_cast<const uint4*>(&WT[(size_t)(n0 + n) * KDIM + c]);
    }

    f32x4 acc[4][2] = {};
    for (int k0 = 0; k0 < KDIM; k0 += 64) {
        __syncthreads();
        if constexpr (sizeof(AT) == 4) {
            #pragma unroll
            for (int it = 0; it < 8; ++it) {
                int f = t + 256 * it;
                int r = f >> 4, c = (f & 15) * 4;
                int row = m0 + r;
                float4 v = make_float4(0.f, 0.f, 0.f, 0.f);
                if (row < M) v = *reinterpret_cast<const float4*>(&A[(size_t)row * KDIM + k0 + c]);
                uint2 pk;
                pk.x = pack_bf2(v.x, v.y);
                pk.y = pack_bf2(v.z, v.w);
                *reinterpret_cast<uint2*>(&As[r * LDA + c]) = pk;
            }
        } else {
            #pragma unroll
            for (int it = 0; it < 4; ++it) {
                int f = t + 256 * it;
                int r = f >> 3, c = (f & 7) * 8;
                int row = m0 + r;
                uint4 v = make_uint4(0u, 0u, 0u, 0u);
                if (row < M) v = *reinterpret_cast<const uint4*>(&A[(size_t)row * KDIM + k0 + c]);
                *reinterpret_cast<uint4*>(&As[r * LDA + c]) = v;
            }
        }
        __syncthreads();
        #pragma unroll
        for (int kk = 0; kk < 64; kk += 32) {
            bf16x8 af[4], bfr[2];
            #pragma unroll
            for (int mi = 0; mi < 4; ++mi)
                af[mi] = *reinterpret_cast<const bf16x8*>(
                    &As[(wm * 64 + mi * 16 + l15) * LDA + kk + quad * 8]);
            #pragma unroll
            for (int ni = 0; ni < 2; ++ni)
                bfr[ni] = *reinterpret_cast<const bf16x8*>(
                    &Bs[(wn * 32 + ni * 16 + l15) * LDB + k0 + kk + quad * 8]);
            #pragma unroll
            for (int mi = 0; mi < 4; ++mi)
                #pragma unroll
                for (int ni = 0; ni < 2; ++ni)
                    acc[mi][ni] = __builtin_amdgcn_mfma_f32_16x16x32_bf16(
                        af[mi], bfr[ni], acc[mi][ni], 0, 0, 0);
        }
    }
    #pragma unroll
    for (int mi = 0; mi < 4; ++mi)
        #pragma unroll
        for (int ni = 0; ni < 2; ++ni)
            #pragma unroll
            for (int r = 0; r < 4; ++r) {
                int row = m0 + wm * 64 + mi * 16 + quad * 4 + r;
                int col = n0 + wn * 32 + ni * 16 + l15;
                if (row < M)
                    C[(size_t)row * NC + col] = __float2bfloat16(acc[mi][ni][r]);
            }
}

// ---------------- layer 1: wave per node, 4 independent edges unrolled, no-max softmax ----
// lane holds features lane*4..+3 of 256 (head = lane/16); logits need only the identity
// softmax(e) == exp(e)/sum(exp(e)) (max-shift cancels; |e| ~ N(0,1.4), safe in fp32).
__global__ void k_node1(const __hip_bfloat16* __restrict__ xl,
                        const __hip_bfloat16* __restrict__ xr,
                        const int* __restrict__ rowstart, const int* __restrict__ csr_src,
                        const float* __restrict__ att,   // [4,64]
                        const float* __restrict__ bias,  // [64]
                        const float* __restrict__ lng,
                        const float* __restrict__ lnb,
                        __hip_bfloat16* __restrict__ h1b) {
    int wid = (blockIdx.x * 256 + threadIdx.x) >> 6;
    int lane = threadIdx.x & 63;
    if (wid >= NNODES) return;
    const int i = wid;
    const int grp = lane >> 4;
    const int c0 = (lane & 15) * 4;
    const int fb = lane * 4;

    const float4 xrv = ldbf4(xr + (size_t)i * 256 + fb);
    const float4 av  = *reinterpret_cast<const float4*>(att + fb);

    float l0 = 0.f, l1 = 0.f, l2 = 0.f, l3 = 0.f;
    float4 A0 = make_float4(0.f, 0.f, 0.f, 0.f);
    float4 A1 = A0, A2 = A0, A3 = A0;

    const int p0 = rowstart[i], p1 = rowstart[i + 1];
    for (int p = p0; p < p1; p += 4) {
        int q1 = (p + 1 < p1) ? p + 1 : p1 - 1;
        int q2 = (p + 2 < p1) ? p + 2 : p1 - 1;
        int q3 = (p + 3 < p1) ? p + 3 : p1 - 1;
        int j0 = csr_src[p];
        int j1 = csr_src[q1];
        int j2 = csr_src[q2];
        int j3 = csr_src[q3];
        float4 x0 = ldbf4(xl + (size_t)j0 * 256 + fb);
        float4 x1 = ldbf4(xl + (size_t)j1 * 256 + fb);
        float4 x2 = ldbf4(xl + (size_t)j2 * 256 + fb);
        float4 x3 = ldbf4(xl + (size_t)j3 * 256 + fb);
        float e0 = edot(x0, xrv, av);
        float e1 = edot(x1, xrv, av);
        float e2 = edot(x2, xrv, av);
        float e3 = edot(x3, xrv, av);
        #pragma unroll
        for (int s = 1; s <= 8; s <<= 1) {
            e0 += __shfl_xor(e0, s);
            e1 += __shfl_xor(e1, s);
            e2 += __shfl_xor(e2, s);
            e3 += __shfl_xor(e3, s);
        }
        float pe0 = __expf(fminf(e0, 60.f));
        float pe1 = (p + 1 < p1) ? __expf(fminf(e1, 60.f)) : 0.f;
        float pe2 = (p + 2 < p1) ? __expf(fminf(e2, 60.f)) : 0.f;
        float pe3 = (p + 3 < p1) ? __expf(fminf(e3, 60.f)) : 0.f;
        l0 += pe0; l1 += pe1; l2 += pe2; l3 += pe3;
        A0.x += pe0 * x0.x; A0.y += pe0 * x0.y; A0.z += pe0 * x0.z; A0.w += pe0 * x0.w;
        A1.x += pe1 * x1.x; A1.y += pe1 * x1.y; A1.z += pe1 * x1.z; A1.w += pe1 * x1.w;
        A2.x += pe2 * x2.x; A2.y += pe2 * x2.y; A2.z += pe2 * x2.z; A2.w += pe2 * x2.w;
        A3.x += pe3 * x3.x; A3.y += pe3 * x3.y; A3.z += pe3 * x3.z; A3.w += pe3 * x3.w;
    }
    float l = (l0 + l1) + (l2 + l3);
    float inv = 1.f / (l + SM_EPS);
    float v0 = ((A0.x + A1.x) + (A2.x + A3.x)) * inv;
    float v1 = ((A0.y + A1.y) + (A2.y + A3.y)) * inv;
    float v2 = ((A0.z + A1.z) + (A2.z + A3.z)) * inv;
    float v3 = ((A0.w + A1.w) + (A2.w + A3.w)) * inv;
    // mean over 4 heads (lanes l, l^16, l^32, l^48 hold same channels)
    v0 += __shfl_xor(v0, 16); v0 += __shfl_xor(v0, 32);
    v1 += __shfl_xor(v1, 16); v1 += __shfl_xor(v1, 32);
    v2 += __shfl_xor(v2, 16); v2 += __shfl_xor(v2, 32);
    v3 += __shfl_xor(v3, 16); v3 += __shfl_xor(v3, 32);
    const float4 bv = *reinterpret_cast<const float4*>(bias + c0);
    float o0 = v0 * 0.25f + bv.x;
    float o1 = v1 * 0.25f + bv.y;
    float o2 = v2 * 0.25f + bv.z;
    float o3 = v3 * 0.25f + bv.w;
    // LayerNorm over 64 channels (each 16-lane group holds a full replica)
    float s1 = o0 + o1 + o2 + o3;
    s1 += __shfl_xor(s1, 1); s1 += __shfl_xor(s1, 2); s1 += __shfl_xor(s1, 4); s1 += __shfl_xor(s1, 8);
    float mu = s1 * 0.015625f;
    float d0 = o0 - mu, d1 = o1 - mu, d2 = o2 - mu, d3 = o3 - mu;
    float s2 = d0 * d0 + d1 * d1 + d2 * d2 + d3 * d3;
    s2 += __shfl_xor(s2, 1); s2 += __shfl_xor(s2, 2); s2 += __shfl_xor(s2, 4); s2 += __shfl_xor(s2, 8);
    float istd = rsqrtf(s2 * 0.015625f + LN_EPS);
    const float4 gv = *reinterpret_cast<const float4*>(lng + c0);
    const float4 bb = *reinterpret_cast<const float4*>(lnb + c0);
    float h0 = fmaxf(d0 * istd * gv.x + bb.x, 0.f);
    float h1 = fmaxf(d1 * istd * gv.y + bb.y, 0.f);
    float h2 = fmaxf(d2 * istd * gv.z + bb.z, 0.f);
    float h3 = fmaxf(d3 * istd * gv.w + bb.w, 0.f);
    if (grp == 0) {
        uint2 pk;
        pk.x = pack_bf2(h0, h1);
        pk.y = pack_bf2(h2, h3);
        *reinterpret_cast<uint2*>(h1b + (size_t)i * 64 + c0) = pk;
    }
}

// ---------------- layer 2: wave per node, 1 feature/lane, 4 edges unrolled, no-max ----
__global__ void k_node2(const __hip_bfloat16* __restrict__ xl,
                        const __hip_bfloat16* __restrict__ xr,
                        const int* __restrict__ rowstart, const int* __restrict__ csr_src,
                        const float* __restrict__ att,   // [64]
                        const float* __restrict__ bias,
                        const float* __restrict__ lng,
                        const float* __restrict__ lnb,
                        float* __restrict__ out) {
    int wid = (blockIdx.x * 256 + threadIdx.x) >> 6;
    int lane = threadIdx.x & 63;
    if (wid >= NNODES) return;
    const int i = wid;
    float xrv = __bfloat162float(xr[(size_t)i * 64 + lane]);
    float a = att[lane];

    float l0 = 0.f, l1 = 0.f, l2 = 0.f, l3 = 0.f;
    float A0 = 0.f, A1 = 0.f, A2 = 0.f, A3 = 0.f;
    const int p0 = rowstart[i], p1 = rowstart[i + 1];
    for (int p = p0; p < p1; p += 4) {
        int q1 = (p + 1 < p1) ? p + 1 : p1 - 1;
        int q2 = (p + 2 < p1) ? p + 2 : p1 - 1;
        int q3 = (p + 3 < p1) ? p + 3 : p1 - 1;
        int j0 = csr_src[p];
        int j1 = csr_src[q1];
        int j2 = csr_src[q2];
        int j3 = csr_src[q3];
        float x0 = __bfloat162float(xl[(size_t)j0 * 64 + lane]);
        float x1 = __bfloat162float(xl[(size_t)j1 * 64 + lane]);
        float x2 = __bfloat162float(xl[(size_t)j2 * 64 + lane]);
        float x3 = __bfloat162float(xl[(size_t)j3 * 64 + lane]);
        float e0 = lrelu(x0 + xrv) * a;
        float e1 = lrelu(x1 + xrv) * a;
        float e2 = lrelu(x2 + xrv) * a;
        float e3 = lrelu(x3 + xrv) * a;
        #pragma unroll
        for (int s = 1; s <= 32; s <<= 1) {
            e0 += __shfl_xor(e0, s);
            e1 += __shfl_xor(e1, s);
            e2 += __shfl_xor(e2, s);
            e3 += __shfl_xor(e3, s);
        }
        float pe0 = __expf(fminf(e0, 60.f));
        float pe1 = (p + 1 < p1) ? __expf(fminf(e1, 60.f)) : 0.f;
        float pe2 = (p + 2 < p1) ? __expf(fminf(e2, 60.f)) : 0.f;
        float pe3 = (p + 3 < p1) ? __expf(fminf(e3, 60.f)) : 0.f;
        l0 += pe0; l1 += pe1; l2 += pe2; l3 += pe3;
        A0 += pe0 * x0; A1 += pe1 * x1; A2 += pe2 * x2; A3 += pe3 * x3;
    }
    float l = (l0 + l1) + (l2 + l3);
    float acc = (A0 + A1) + (A2 + A3);
    float v = acc / (l + SM_EPS) + bias[lane];
    float s1 = v;
    s1 += __shfl_xor(s1, 1); s1 += __shfl_xor(s1, 2); s1 += __shfl_xor(s1, 4);
    s1 += __shfl_xor(s1, 8); s1 += __shfl_xor(s1, 16); s1 += __shfl_xor(s1, 32);
    float mu = s1 * 0.015625f;
    float d = v - mu;
    float s2 = d * d;
    s2 += __shfl_xor(s2, 1); s2 += __shfl_xor(s2, 2); s2 += __shfl_xor(s2, 4);
    s2 += __shfl_xor(s2, 8); s2 += __shfl_xor(s2, 16); s2 += __shfl_xor(s2, 32);
    float istd = rsqrtf(s2 * 0.015625f + LN_EPS);
    out[(size_t)i * 64 + lane] = d * istd * lng[lane] + lnb[lane];
}

extern "C" void kernel_launch(void* const* d_in, const int* in_sizes, int n_in,
                              void* d_out, int out_size, void* d_ws, size_t ws_size,
                              hipStream_t stream) {
    const float* x    = (const float*)d_in[0];
    const int*   ei   = (const int*)d_in[1];
    const float* W1l  = (const float*)d_in[2];
    const float* W1r  = (const float*)d_in[3];
    const float* att1 = (const float*)d_in[4];
    const float* b1   = (const float*)d_in[5];
    const float* ln1g = (const float*)d_in[6];
    const float* ln1b = (const float*)d_in[7];
    const float* W2l  = (const float*)d_in[8];
    const float* W2r  = (const float*)d_in[9];
    const float* att2 = (const float*)d_in[10];
    const float* b2   = (const float*)d_in[11];
    const float* ln2g = (const float*)d_in[12];
    const float* ln2b = (const float*)d_in[13];
    float* out = (float*)d_out;

    char* w = (char*)d_ws;
    size_t off = 0;
    auto alloc = [&](size_t bytes) -> void* {
        void* p = w + off;
        off += (bytes + 255) & ~(size_t)255;
        return p;
    };
    __hip_bfloat16* xl1  = (__hip_bfloat16*)alloc((size_t)NNODES * 256 * 2);
    __hip_bfloat16* xr1  = (__hip_bfloat16*)alloc((size_t)NNODES * 256 * 2);
    __hip_bfloat16* h1b  = (__hip_bfloat16*)alloc((size_t)NNODES * 64 * 2);
    __hip_bfloat16* xl2  = (__hip_bfloat16*)alloc((size_t)NNODES * 64 * 2);
    __hip_bfloat16* xr2  = (__hip_bfloat16*)alloc((size_t)NNODES * 64 * 2);
    __hip_bfloat16* w1lT = (__hip_bfloat16*)alloc(256 * 256 * 2);
    __hip_bfloat16* w1rT = (__hip_bfloat16*)alloc(256 * 256 * 2);
    __hip_bfloat16* w2lT = (__hip_bfloat16*)alloc(64 * 64 * 2);
    __hip_bfloat16* w2rT = (__hip_bfloat16*)alloc(64 * 64 * 2);
    int* deg      = (int*)alloc((size_t)NNODES * 4);
    int* rowstart = (int*)alloc((size_t)(NNODES + 1) * 4);
    int* cursor   = (int*)alloc((size_t)NNODES * 4);
    int* csr_src  = (int*)alloc((size_t)ETOT * 4);
    int* blocksum = (int*)alloc(1024);
    (void)ws_size; (void)in_sizes; (void)n_in; (void)out_size;

    hipMemsetAsync(deg, 0, (size_t)NNODES * 4, stream);
    const int histB = (ETOT + 255) / 256;
    const int scanB = (NNODES + 255) / 256;
    k_hist<<<histB, 256, 0, stream>>>(ei, deg);
    k_scan1<<<scanB, 256, 0, stream>>>(deg, rowstart, blocksum);
    k_scan2<<<1, 256, 0, stream>>>(blocksum, scanB);
    k_scan3<<<scanB, 256, 0, stream>>>(rowstart, blocksum, cursor);
    k_scatter<<<histB, 256, 0, stream>>>(ei, cursor, csr_src);

    k_cast_w<<<544, 256, 0, stream>>>(W1l, W1r, W2l, W2r, w1lT, w1rT, w2lT, w2rT);

    dim3 gm1((NNODES + GBM - 1) / GBM, 256 / GBN);   // (391, 4)
    k_gemm_mfma<256, 256, float><<<gm1, 256, 0, stream>>>(x, w1lT, xl1, NNODES);
    k_gemm_mfma<256, 256, float><<<gm1, 256, 0, stream>>>(x, w1rT, xr1, NNODES);
    k_node1<<<(NNODES + 3) / 4, 256, 0, stream>>>(xl1, xr1, rowstart, csr_src,
                                                  att1, b1, ln1g, ln1b, h1b);
    dim3 gm2((NNODES + GBM - 1) / GBM, 1);           // (391, 1)
    k_gemm_mfma<64, 64, __hip_bfloat16><<<gm2, 256, 0, stream>>>(h1b, w2lT, xl2, NNODES);
    k_gemm_mfma<64, 64, __hip_bfloat16><<<gm2, 256, 0, stream>>>(h1b, w2rT, xr2, NNODES);
    k_node2<<<(NNODES + 3) / 4, 256, 0, stream>>>(xl2, xr2, rowstart, csr_src,
                                                  att2, b2, ln2g, ln2b, out);
}

// Round 6
// 397.487 us; speedup vs baseline: 1.7250x; 1.1833x over previous
//
#include <hip/hip_runtime.h>
#include <hip/hip_bf16.h>

#define NNODES 50000
#define NEDGES 800000
#define ETOT   850000
#define NEG_SLOPE 0.2f
#define LN_EPS 1e-5f
#define SM_EPS 1e-16f

typedef short bf16x8 __attribute__((ext_vector_type(8)));
typedef float f32x4  __attribute__((ext_vector_type(4)));

__device__ __forceinline__ float lrelu(float x) { return fmaxf(x, NEG_SLOPE * x); }

__device__ __forceinline__ float4 ldbf4(const __hip_bfloat16* p) {
    uint2 raw = *reinterpret_cast<const uint2*>(p);
    __hip_bfloat162 ab = *reinterpret_cast<__hip_bfloat162*>(&raw.x);
    __hip_bfloat162 cd = *reinterpret_cast<__hip_bfloat162*>(&raw.y);
    float2 f0 = __bfloat1622float2(ab);
    float2 f1 = __bfloat1622float2(cd);
    return make_float4(f0.x, f0.y, f1.x, f1.y);
}

__device__ __forceinline__ unsigned pack_bf2(float a, float b) {
    __hip_bfloat162 p;
    p.x = __float2bfloat16(a);
    p.y = __float2bfloat16(b);
    return *reinterpret_cast<unsigned*>(&p);
}

__device__ __forceinline__ float edot(const float4& x, const float4& xr, const float4& a) {
    float t0 = lrelu(x.x + xr.x);
    float t1 = lrelu(x.y + xr.y);
    float t2 = lrelu(x.z + xr.z);
    float t3 = lrelu(x.w + xr.w);
    return t0 * a.x + t1 * a.y + t2 * a.z + t3 * a.w;
}

// ---------------- cast x -> bf16 (8 elems/thread) ----------------
__global__ void k_cast_x(const float* __restrict__ X, __hip_bfloat16* __restrict__ Y, int n8) {
    int i = blockIdx.x * 256 + threadIdx.x;
    if (i >= n8) return;
    float4 a = reinterpret_cast<const float4*>(X)[2 * i];
    float4 b = reinterpret_cast<const float4*>(X)[2 * i + 1];
    uint4 o;
    o.x = pack_bf2(a.x, a.y);
    o.y = pack_bf2(a.z, a.w);
    o.z = pack_bf2(b.x, b.y);
    o.w = pack_bf2(b.z, b.w);
    reinterpret_cast<uint4*>(Y)[i] = o;
}

// ---------------- combined weight transpose+cast ----------------
__global__ void k_cast_w(const float* __restrict__ W1l, const float* __restrict__ W1r,
                         const float* __restrict__ W2l, const float* __restrict__ W2r,
                         __hip_bfloat16* __restrict__ w1lT, __hip_bfloat16* __restrict__ w1rT,
                         __hip_bfloat16* __restrict__ w2lT, __hip_bfloat16* __restrict__ w2rT) {
    int t = blockIdx.x * 256 + threadIdx.x;
    if (t < 65536) {
        int k = t >> 8, n = t & 255;
        w1lT[n * 256 + k] = __float2bfloat16(W1l[t]);
    } else if (t < 131072) {
        int u = t - 65536; int k = u >> 8, n = u & 255;
        w1rT[n * 256 + k] = __float2bfloat16(W1r[u]);
    } else if (t < 135168) {
        int u = t - 131072; int k = u >> 6, n = u & 63;
        w2lT[n * 64 + k] = __float2bfloat16(W2l[u]);
    } else if (t < 139264) {
        int u = t - 135168; int k = u >> 6, n = u & 63;
        w2rT[n * 64 + k] = __float2bfloat16(W2r[u]);
    }
}

// ---------------- CSR build ----------------
__global__ void k_hist(const int* __restrict__ ei, int* __restrict__ deg) {
    int e = blockIdx.x * 256 + threadIdx.x;
    if (e >= ETOT) return;
    int dst = (e < NEDGES) ? ei[NEDGES + e] : (e - NEDGES);
    atomicAdd(&deg[dst], 1);
}

__global__ void k_scan1(const int* __restrict__ deg, int* __restrict__ rowstart,
                        int* __restrict__ blocksum) {
    __shared__ int s[256];
    int t = threadIdx.x;
    int i = blockIdx.x * 256 + t;
    int v = (i < NNODES) ? deg[i] : 0;
    s[t] = v;
    __syncthreads();
    #pragma unroll
    for (int off = 1; off < 256; off <<= 1) {
        int add = (t >= off) ? s[t - off] : 0;
        __syncthreads();
        s[t] += add;
        __syncthreads();
    }
    if (i < NNODES) rowstart[i] = s[t] - v;
    if (t == 255) blocksum[blockIdx.x] = s[255];
}

__global__ void k_scan2(int* __restrict__ bs, int nb) {
    __shared__ int s[256];
    int t = threadIdx.x;
    int v = (t < nb) ? bs[t] : 0;
    s[t] = v;
    __syncthreads();
    #pragma unroll
    for (int off = 1; off < 256; off <<= 1) {
        int add = (t >= off) ? s[t - off] : 0;
        __syncthreads();
        s[t] += add;
        __syncthreads();
    }
    if (t < nb) bs[t] = s[t] - v;
}

__global__ void k_scan3(int* __restrict__ rowstart, const int* __restrict__ boff,
                        int* __restrict__ cursor) {
    int i = blockIdx.x * 256 + threadIdx.x;
    if (i < NNODES) {
        int r = rowstart[i] + boff[i >> 8];
        rowstart[i] = r;
        cursor[i] = r;
    } else if (i == NNODES) {
        rowstart[NNODES] = ETOT;
    }
}

__global__ void k_scatter(const int* __restrict__ ei, int* __restrict__ cursor,
                          int* __restrict__ csr_src) {
    int e = blockIdx.x * 256 + threadIdx.x;
    if (e >= ETOT) return;
    int src, dst;
    if (e < NEDGES) { src = ei[e]; dst = ei[NEDGES + e]; }
    else { src = e - NEDGES; dst = src; }
    int pos = atomicAdd(&cursor[dst], 1);
    csr_src[pos] = src;
}

// ---------------- dual-output MFMA bf16 GEMM ----------------
// Cl = A @ WTl^T, Cr = A @ WTr^T.  A: [M,KDIM] bf16. WT*: [NC][KDIM] bf16.
// Tile 128x64, 4 waves, per-k0 staging of As + both B slices. LDS 36.9 KB.
template <int KDIM, int NC>
__global__ __launch_bounds__(256) void k_gemm_dual(
    const __hip_bfloat16* __restrict__ A,
    const __hip_bfloat16* __restrict__ WTl,
    const __hip_bfloat16* __restrict__ WTr,
    __hip_bfloat16* __restrict__ Cl,
    __hip_bfloat16* __restrict__ Cr, int M)
{
    __shared__ short As[128 * 72];
    __shared__ short Bls[64 * 72];
    __shared__ short Brs[64 * 72];
    const int t = threadIdx.x;
    const int m0 = blockIdx.x * 128;
    const int n0 = blockIdx.y * 64;
    const int wave = t >> 6, lane = t & 63;
    const int wm = wave & 1, wn = wave >> 1;
    const int l15 = lane & 15, quad = lane >> 4;

    f32x4 accl[4][2] = {};
    f32x4 accr[4][2] = {};
    for (int k0 = 0; k0 < KDIM; k0 += 64) {
        __syncthreads();
        #pragma unroll
        for (int it = 0; it < 4; ++it) {          // As: 128 rows x 64 cols
            int f = t + 256 * it;
            int r = f >> 3, c = (f & 7) * 8;
            int row = m0 + r;
            uint4 v = make_uint4(0u, 0u, 0u, 0u);
            if (row < M) v = *reinterpret_cast<const uint4*>(&A[(size_t)row * KDIM + k0 + c]);
            *reinterpret_cast<uint4*>(&As[r * 72 + c]) = v;
        }
        #pragma unroll
        for (int it = 0; it < 2; ++it) {          // Bl/Br: 64 rows x 64 cols each
            int f = t + 256 * it;
            int n = f >> 3, c = (f & 7) * 8;
            *reinterpret_cast<uint4*>(&Bls[n * 72 + c]) =
                *reinterpret_cast<const uint4*>(&WTl[(size_t)(n0 + n) * KDIM + k0 + c]);
            *reinterpret_cast<uint4*>(&Brs[n * 72 + c]) =
                *reinterpret_cast<const uint4*>(&WTr[(size_t)(n0 + n) * KDIM + k0 + c]);
        }
        __syncthreads();
        #pragma unroll
        for (int kk = 0; kk < 64; kk += 32) {
            bf16x8 af[4], bl[2], br[2];
            #pragma unroll
            for (int mi = 0; mi < 4; ++mi)
                af[mi] = *reinterpret_cast<const bf16x8*>(
                    &As[(wm * 64 + mi * 16 + l15) * 72 + kk + quad * 8]);
            #pragma unroll
            for (int ni = 0; ni < 2; ++ni) {
                bl[ni] = *reinterpret_cast<const bf16x8*>(
                    &Bls[(wn * 32 + ni * 16 + l15) * 72 + kk + quad * 8]);
                br[ni] = *reinterpret_cast<const bf16x8*>(
                    &Brs[(wn * 32 + ni * 16 + l15) * 72 + kk + quad * 8]);
            }
            #pragma unroll
            for (int mi = 0; mi < 4; ++mi)
                #pragma unroll
                for (int ni = 0; ni < 2; ++ni) {
                    accl[mi][ni] = __builtin_amdgcn_mfma_f32_16x16x32_bf16(
                        af[mi], bl[ni], accl[mi][ni], 0, 0, 0);
                    accr[mi][ni] = __builtin_amdgcn_mfma_f32_16x16x32_bf16(
                        af[mi], br[ni], accr[mi][ni], 0, 0, 0);
                }
        }
    }
    #pragma unroll
    for (int mi = 0; mi < 4; ++mi)
        #pragma unroll
        for (int ni = 0; ni < 2; ++ni)
            #pragma unroll
            for (int r = 0; r < 4; ++r) {
                int row = m0 + wm * 64 + mi * 16 + quad * 4 + r;
                int col = n0 + wn * 32 + ni * 16 + l15;
                if (row < M) {
                    Cl[(size_t)row * NC + col] = __float2bfloat16(accl[mi][ni][r]);
                    Cr[(size_t)row * NC + col] = __float2bfloat16(accr[mi][ni][r]);
                }
            }
}

// ---------------- layer 1: wave per node, 4 edges unrolled, no-max softmax ----
__global__ void k_node1(const __hip_bfloat16* __restrict__ xl,
                        const __hip_bfloat16* __restrict__ xr,
                        const int* __restrict__ rowstart, const int* __restrict__ csr_src,
                        const float* __restrict__ att,   // [4,64]
                        const float* __restrict__ bias,  // [64]
                        const float* __restrict__ lng,
                        const float* __restrict__ lnb,
                        __hip_bfloat16* __restrict__ h1b) {
    int wid = (blockIdx.x * 256 + threadIdx.x) >> 6;
    int lane = threadIdx.x & 63;
    if (wid >= NNODES) return;
    const int i = wid;
    const int grp = lane >> 4;
    const int c0 = (lane & 15) * 4;
    const int fb = lane * 4;

    const float4 xrv = ldbf4(xr + (size_t)i * 256 + fb);
    const float4 av  = *reinterpret_cast<const float4*>(att + fb);

    float l0 = 0.f, l1 = 0.f, l2 = 0.f, l3 = 0.f;
    float4 A0 = make_float4(0.f, 0.f, 0.f, 0.f);
    float4 A1 = A0, A2 = A0, A3 = A0;

    const int p0 = rowstart[i], p1 = rowstart[i + 1];
    for (int p = p0; p < p1; p += 4) {
        int q1 = (p + 1 < p1) ? p + 1 : p1 - 1;
        int q2 = (p + 2 < p1) ? p + 2 : p1 - 1;
        int q3 = (p + 3 < p1) ? p + 3 : p1 - 1;
        int j0 = csr_src[p];
        int j1 = csr_src[q1];
        int j2 = csr_src[q2];
        int j3 = csr_src[q3];
        float4 x0 = ldbf4(xl + (size_t)j0 * 256 + fb);
        float4 x1 = ldbf4(xl + (size_t)j1 * 256 + fb);
        float4 x2 = ldbf4(xl + (size_t)j2 * 256 + fb);
        float4 x3 = ldbf4(xl + (size_t)j3 * 256 + fb);
        float e0 = edot(x0, xrv, av);
        float e1 = edot(x1, xrv, av);
        float e2 = edot(x2, xrv, av);
        float e3 = edot(x3, xrv, av);
        #pragma unroll
        for (int s = 1; s <= 8; s <<= 1) {
            e0 += __shfl_xor(e0, s);
            e1 += __shfl_xor(e1, s);
            e2 += __shfl_xor(e2, s);
            e3 += __shfl_xor(e3, s);
        }
        float pe0 = __expf(fminf(e0, 60.f));
        float pe1 = (p + 1 < p1) ? __expf(fminf(e1, 60.f)) : 0.f;
        float pe2 = (p + 2 < p1) ? __expf(fminf(e2, 60.f)) : 0.f;
        float pe3 = (p + 3 < p1) ? __expf(fminf(e3, 60.f)) : 0.f;
        l0 += pe0; l1 += pe1; l2 += pe2; l3 += pe3;
        A0.x += pe0 * x0.x; A0.y += pe0 * x0.y; A0.z += pe0 * x0.z; A0.w += pe0 * x0.w;
        A1.x += pe1 * x1.x; A1.y += pe1 * x1.y; A1.z += pe1 * x1.z; A1.w += pe1 * x1.w;
        A2.x += pe2 * x2.x; A2.y += pe2 * x2.y; A2.z += pe2 * x2.z; A2.w += pe2 * x2.w;
        A3.x += pe3 * x3.x; A3.y += pe3 * x3.y; A3.z += pe3 * x3.z; A3.w += pe3 * x3.w;
    }
    float l = (l0 + l1) + (l2 + l3);
    float inv = 1.f / (l + SM_EPS);
    float v0 = ((A0.x + A1.x) + (A2.x + A3.x)) * inv;
    float v1 = ((A0.y + A1.y) + (A2.y + A3.y)) * inv;
    float v2 = ((A0.z + A1.z) + (A2.z + A3.z)) * inv;
    float v3 = ((A0.w + A1.w) + (A2.w + A3.w)) * inv;
    v0 += __shfl_xor(v0, 16); v0 += __shfl_xor(v0, 32);
    v1 += __shfl_xor(v1, 16); v1 += __shfl_xor(v1, 32);
    v2 += __shfl_xor(v2, 16); v2 += __shfl_xor(v2, 32);
    v3 += __shfl_xor(v3, 16); v3 += __shfl_xor(v3, 32);
    const float4 bv = *reinterpret_cast<const float4*>(bias + c0);
    float o0 = v0 * 0.25f + bv.x;
    float o1 = v1 * 0.25f + bv.y;
    float o2 = v2 * 0.25f + bv.z;
    float o3 = v3 * 0.25f + bv.w;
    float s1 = o0 + o1 + o2 + o3;
    s1 += __shfl_xor(s1, 1); s1 += __shfl_xor(s1, 2); s1 += __shfl_xor(s1, 4); s1 += __shfl_xor(s1, 8);
    float mu = s1 * 0.015625f;
    float d0 = o0 - mu, d1 = o1 - mu, d2 = o2 - mu, d3 = o3 - mu;
    float s2 = d0 * d0 + d1 * d1 + d2 * d2 + d3 * d3;
    s2 += __shfl_xor(s2, 1); s2 += __shfl_xor(s2, 2); s2 += __shfl_xor(s2, 4); s2 += __shfl_xor(s2, 8);
    float istd = rsqrtf(s2 * 0.015625f + LN_EPS);
    const float4 gv = *reinterpret_cast<const float4*>(lng + c0);
    const float4 bb = *reinterpret_cast<const float4*>(lnb + c0);
    float h0 = fmaxf(d0 * istd * gv.x + bb.x, 0.f);
    float h1 = fmaxf(d1 * istd * gv.y + bb.y, 0.f);
    float h2 = fmaxf(d2 * istd * gv.z + bb.z, 0.f);
    float h3 = fmaxf(d3 * istd * gv.w + bb.w, 0.f);
    if (grp == 0) {
        uint2 pk;
        pk.x = pack_bf2(h0, h1);
        pk.y = pack_bf2(h2, h3);
        *reinterpret_cast<uint2*>(h1b + (size_t)i * 64 + c0) = pk;
    }
}

// ---------------- layer 2: 16-lane group per edge (4 ch/lane), no-max, final LN ----
__global__ void k_node2(const __hip_bfloat16* __restrict__ xl,
                        const __hip_bfloat16* __restrict__ xr,
                        const int* __restrict__ rowstart, const int* __restrict__ csr_src,
                        const float* __restrict__ att,   // [64]
                        const float* __restrict__ bias,
                        const float* __restrict__ lng,
                        const float* __restrict__ lnb,
                        float* __restrict__ out) {
    int wid = (blockIdx.x * 256 + threadIdx.x) >> 6;
    int lane = threadIdx.x & 63;
    if (wid >= NNODES) return;
    const int i = wid;
    const int grp = lane >> 4;
    const int c0 = (lane & 15) * 4;

    const float4 xrv = ldbf4(xr + (size_t)i * 64 + c0);
    const float4 av  = *reinterpret_cast<const float4*>(att + c0);
    float l = 0.f;
    float4 A = make_float4(0.f, 0.f, 0.f, 0.f);

    const int p0 = rowstart[i], p1 = rowstart[i + 1];
    for (int p = p0; p < p1; p += 4) {
        int pe = p + grp;
        bool valid = pe < p1;
        int j = csr_src[valid ? pe : p1 - 1];
        float4 xlv = ldbf4(xl + (size_t)j * 64 + c0);
        float e = edot(xlv, xrv, av);
        e += __shfl_xor(e, 1); e += __shfl_xor(e, 2); e += __shfl_xor(e, 4); e += __shfl_xor(e, 8);
        float w = valid ? __expf(fminf(e, 60.f)) : 0.f;
        l += w;
        A.x += w * xlv.x;
        A.y += w * xlv.y;
        A.z += w * xlv.z;
        A.w += w * xlv.w;
    }
    // sum partial states across the 4 groups (plain adds — no max state)
    #pragma unroll
    for (int s = 16; s <= 32; s <<= 1) {
        l   += __shfl_xor(l, s);
        A.x += __shfl_xor(A.x, s);
        A.y += __shfl_xor(A.y, s);
        A.z += __shfl_xor(A.z, s);
        A.w += __shfl_xor(A.w, s);
    }
    float inv = 1.f / (l + SM_EPS);
    const float4 bv = *reinterpret_cast<const float4*>(bias + c0);
    float o0 = A.x * inv + bv.x;
    float o1 = A.y * inv + bv.y;
    float o2 = A.z * inv + bv.z;
    float o3 = A.w * inv + bv.w;
    float s1 = o0 + o1 + o2 + o3;
    s1 += __shfl_xor(s1, 1); s1 += __shfl_xor(s1, 2); s1 += __shfl_xor(s1, 4); s1 += __shfl_xor(s1, 8);
    float mu = s1 * 0.015625f;
    float d0 = o0 - mu, d1 = o1 - mu, d2 = o2 - mu, d3 = o3 - mu;
    float s2 = d0 * d0 + d1 * d1 + d2 * d2 + d3 * d3;
    s2 += __shfl_xor(s2, 1); s2 += __shfl_xor(s2, 2); s2 += __shfl_xor(s2, 4); s2 += __shfl_xor(s2, 8);
    float istd = rsqrtf(s2 * 0.015625f + LN_EPS);
    const float4 gv = *reinterpret_cast<const float4*>(lng + c0);
    const float4 bb = *reinterpret_cast<const float4*>(lnb + c0);
    if (grp == 0) {
        float4 y;
        y.x = d0 * istd * gv.x + bb.x;
        y.y = d1 * istd * gv.y + bb.y;
        y.z = d2 * istd * gv.z + bb.z;
        y.w = d3 * istd * gv.w + bb.w;
        *reinterpret_cast<float4*>(out + (size_t)i * 64 + c0) = y;
    }
}

extern "C" void kernel_launch(void* const* d_in, const int* in_sizes, int n_in,
                              void* d_out, int out_size, void* d_ws, size_t ws_size,
                              hipStream_t stream) {
    const float* x    = (const float*)d_in[0];
    const int*   ei   = (const int*)d_in[1];
    const float* W1l  = (const float*)d_in[2];
    const float* W1r  = (const float*)d_in[3];
    const float* att1 = (const float*)d_in[4];
    const float* b1   = (const float*)d_in[5];
    const float* ln1g = (const float*)d_in[6];
    const float* ln1b = (const float*)d_in[7];
    const float* W2l  = (const float*)d_in[8];
    const float* W2r  = (const float*)d_in[9];
    const float* att2 = (const float*)d_in[10];
    const float* b2   = (const float*)d_in[11];
    const float* ln2g = (const float*)d_in[12];
    const float* ln2b = (const float*)d_in[13];
    float* out = (float*)d_out;

    char* w = (char*)d_ws;
    size_t off = 0;
    auto alloc = [&](size_t bytes) -> void* {
        void* p = w + off;
        off += (bytes + 255) & ~(size_t)255;
        return p;
    };
    __hip_bfloat16* xb   = (__hip_bfloat16*)alloc((size_t)NNODES * 256 * 2);
    __hip_bfloat16* xl1  = (__hip_bfloat16*)alloc((size_t)NNODES * 256 * 2);
    __hip_bfloat16* xr1  = (__hip_bfloat16*)alloc((size_t)NNODES * 256 * 2);
    __hip_bfloat16* h1b  = (__hip_bfloat16*)alloc((size_t)NNODES * 64 * 2);
    __hip_bfloat16* xl2  = (__hip_bfloat16*)alloc((size_t)NNODES * 64 * 2);
    __hip_bfloat16* xr2  = (__hip_bfloat16*)alloc((size_t)NNODES * 64 * 2);
    __hip_bfloat16* w1lT = (__hip_bfloat16*)alloc(256 * 256 * 2);
    __hip_bfloat16* w1rT = (__hip_bfloat16*)alloc(256 * 256 * 2);
    __hip_bfloat16* w2lT = (__hip_bfloat16*)alloc(64 * 64 * 2);
    __hip_bfloat16* w2rT = (__hip_bfloat16*)alloc(64 * 64 * 2);
    int* deg      = (int*)alloc((size_t)NNODES * 4);
    int* rowstart = (int*)alloc((size_t)(NNODES + 1) * 4);
    int* cursor   = (int*)alloc((size_t)NNODES * 4);
    int* csr_src  = (int*)alloc((size_t)ETOT * 4);
    int* blocksum = (int*)alloc(1024);
    (void)ws_size; (void)in_sizes; (void)n_in; (void)out_size;

    hipMemsetAsync(deg, 0, (size_t)NNODES * 4, stream);
    const int histB = (ETOT + 255) / 256;
    const int scanB = (NNODES + 255) / 256;
    k_hist<<<histB, 256, 0, stream>>>(ei, deg);
    k_scan1<<<scanB, 256, 0, stream>>>(deg, rowstart, blocksum);
    k_scan2<<<1, 256, 0, stream>>>(blocksum, scanB);
    k_scan3<<<scanB, 256, 0, stream>>>(rowstart, blocksum, cursor);
    k_scatter<<<histB, 256, 0, stream>>>(ei, cursor, csr_src);

    k_cast_x<<<(NNODES * 256 / 8 + 255) / 256, 256, 0, stream>>>(x, xb, NNODES * 256 / 8);
    k_cast_w<<<544, 256, 0, stream>>>(W1l, W1r, W2l, W2r, w1lT, w1rT, w2lT, w2rT);

    dim3 gm1((NNODES + 127) / 128, 4);
    k_gemm_dual<256, 256><<<gm1, 256, 0, stream>>>(xb, w1lT, w1rT, xl1, xr1, NNODES);
    k_node1<<<(NNODES + 3) / 4, 256, 0, stream>>>(xl1, xr1, rowstart, csr_src,
                                                  att1, b1, ln1g, ln1b, h1b);
    dim3 gm2((NNODES + 127) / 128, 1);
    k_gemm_dual<64, 64><<<gm2, 256, 0, stream>>>(h1b, w2lT, w2rT, xl2, xr2, NNODES);
    k_node2<<<(NNODES + 3) / 4, 256, 0, stream>>>(xl2, xr2, rowstart, csr_src,
                                                  att2, b2, ln2g, ln2b, out);
}

// Round 7
// 364.315 us; speedup vs baseline: 1.8821x; 1.0911x over previous
//
#include <hip/hip_runtime.h>
#include <hip/hip_bf16.h>

#define NNODES 50000
#define NEDGES 800000
#define ETOT   850000
#define NEG_SLOPE 0.2f
#define LN_EPS 1e-5f
#define SM_EPS 1e-16f

typedef short bf16x8 __attribute__((ext_vector_type(8)));
typedef float f32x4  __attribute__((ext_vector_type(4)));
typedef float v2f    __attribute__((ext_vector_type(2)));

__device__ __forceinline__ unsigned pack_bf2(float a, float b) {
    __hip_bfloat162 p;
    p.x = __float2bfloat16(a);
    p.y = __float2bfloat16(b);
    return *reinterpret_cast<unsigned*>(&p);
}

// packed bf16 pair (u32) -> 2 floats (shift/mask, 2 VALU)
__device__ __forceinline__ v2f bf2_to_f2(unsigned u) {
    v2f r;
    r.x = __int_as_float((int)(u << 16));
    r.y = __int_as_float((int)(u & 0xFFFF0000u));
    return r;
}

// pure-VALU 16-lane sum-broadcast: quad xor1, xor2, then row rotate 4, 8
template <int CTRL>
__device__ __forceinline__ float dpp_add(float x) {
    return x + __int_as_float(__builtin_amdgcn_update_dpp(
        0, __float_as_int(x), CTRL, 0xF, 0xF, true));
}
__device__ __forceinline__ float red16(float x) {
    x = dpp_add<0xB1>(x);    // quad_perm(1,0,3,2)  = xor 1
    x = dpp_add<0x4E>(x);    // quad_perm(2,3,0,1)  = xor 2
    x = dpp_add<0x124>(x);   // row_ror:4
    x = dpp_add<0x128>(x);   // row_ror:8
    return x;
}

// packed edge-logit partial over this lane's 4 channels
__device__ __forceinline__ float edot2(v2f x01, v2f x23, v2f xr01, v2f xr23,
                                       v2f a01, v2f a23) {
    v2f s01 = x01 + xr01;
    v2f s23 = x23 + xr23;
    v2f t01 = __builtin_elementwise_max(s01, s01 * NEG_SLOPE);
    v2f t23 = __builtin_elementwise_max(s23, s23 * NEG_SLOPE);
    v2f d = t01 * a01 + t23 * a23;
    return d.x + d.y;
}

// ---------------- fused prep: zero deg + cast x + cast/transpose all weights ----------------
__global__ void k_cast_all(const float* __restrict__ X, __hip_bfloat16* __restrict__ XB,
                           const float* __restrict__ W1l, const float* __restrict__ W1r,
                           const float* __restrict__ W2l, const float* __restrict__ W2r,
                           __hip_bfloat16* __restrict__ w1lT, __hip_bfloat16* __restrict__ w1rT,
                           __hip_bfloat16* __restrict__ w2lT, __hip_bfloat16* __restrict__ w2rT,
                           int* __restrict__ deg) {
    int tid = blockIdx.x * 256 + threadIdx.x;
    if (tid < NNODES) deg[tid] = 0;
    if (tid < 1600000) {             // x: 12.8M elems, 8 per thread
        float4 a = reinterpret_cast<const float4*>(X)[2 * tid];
        float4 b = reinterpret_cast<const float4*>(X)[2 * tid + 1];
        uint4 o;
        o.x = pack_bf2(a.x, a.y);
        o.y = pack_bf2(a.z, a.w);
        o.z = pack_bf2(b.x, b.y);
        o.w = pack_bf2(b.z, b.w);
        reinterpret_cast<uint4*>(XB)[tid] = o;
    } else {
        int t = tid - 1600000;
        if (t < 65536) {
            int k = t >> 8, n = t & 255;
            w1lT[n * 256 + k] = __float2bfloat16(W1l[t]);
        } else if (t < 131072) {
            int u = t - 65536; int k = u >> 8, n = u & 255;
            w1rT[n * 256 + k] = __float2bfloat16(W1r[u]);
        } else if (t < 135168) {
            int u = t - 131072; int k = u >> 6, n = u & 63;
            w2lT[n * 64 + k] = __float2bfloat16(W2l[u]);
        } else if (t < 139264) {
            int u = t - 135168; int k = u >> 6, n = u & 63;
            w2rT[n * 64 + k] = __float2bfloat16(W2r[u]);
        }
    }
}

// ---------------- CSR build ----------------
__global__ void k_hist(const int* __restrict__ ei, int* __restrict__ deg) {
    int e = blockIdx.x * 256 + threadIdx.x;
    if (e >= ETOT) return;
    int dst = (e < NEDGES) ? ei[NEDGES + e] : (e - NEDGES);
    atomicAdd(&deg[dst], 1);
}

__global__ void k_scan1(const int* __restrict__ deg, int* __restrict__ rowstart,
                        int* __restrict__ blocksum) {
    __shared__ int s[256];
    int t = threadIdx.x;
    int i = blockIdx.x * 256 + t;
    int v = (i < NNODES) ? deg[i] : 0;
    s[t] = v;
    __syncthreads();
    #pragma unroll
    for (int off = 1; off < 256; off <<= 1) {
        int add = (t >= off) ? s[t - off] : 0;
        __syncthreads();
        s[t] += add;
        __syncthreads();
    }
    if (i < NNODES) rowstart[i] = s[t] - v;
    if (t == 255) blocksum[blockIdx.x] = s[255];
}

__global__ void k_scan2(int* __restrict__ bs, int nb) {
    __shared__ int s[256];
    int t = threadIdx.x;
    int v = (t < nb) ? bs[t] : 0;
    s[t] = v;
    __syncthreads();
    #pragma unroll
    for (int off = 1; off < 256; off <<= 1) {
        int add = (t >= off) ? s[t - off] : 0;
        __syncthreads();
        s[t] += add;
        __syncthreads();
    }
    if (t < nb) bs[t] = s[t] - v;
}

__global__ void k_scan3(int* __restrict__ rowstart, const int* __restrict__ boff,
                        int* __restrict__ cursor) {
    int i = blockIdx.x * 256 + threadIdx.x;
    if (i < NNODES) {
        int r = rowstart[i] + boff[i >> 8];
        rowstart[i] = r;
        cursor[i] = r;
    } else if (i == NNODES) {
        rowstart[NNODES] = ETOT;
    }
}

__global__ void k_scatter(const int* __restrict__ ei, int* __restrict__ cursor,
                          int* __restrict__ csr_src) {
    int e = blockIdx.x * 256 + threadIdx.x;
    if (e >= ETOT) return;
    int src, dst;
    if (e < NEDGES) { src = ei[e]; dst = ei[NEDGES + e]; }
    else { src = e - NEDGES; dst = src; }
    int pos = atomicAdd(&cursor[dst], 1);
    csr_src[pos] = src;
}

// ---------------- dual-output MFMA bf16 GEMM ----------------
template <int KDIM, int NC>
__global__ __launch_bounds__(256) void k_gemm_dual(
    const __hip_bfloat16* __restrict__ A,
    const __hip_bfloat16* __restrict__ WTl,
    const __hip_bfloat16* __restrict__ WTr,
    __hip_bfloat16* __restrict__ Cl,
    __hip_bfloat16* __restrict__ Cr, int M)
{
    __shared__ short As[128 * 72];
    __shared__ short Bls[64 * 72];
    __shared__ short Brs[64 * 72];
    const int t = threadIdx.x;
    const int m0 = blockIdx.x * 128;
    const int n0 = blockIdx.y * 64;
    const int wave = t >> 6, lane = t & 63;
    const int wm = wave & 1, wn = wave >> 1;
    const int l15 = lane & 15, quad = lane >> 4;

    f32x4 accl[4][2] = {};
    f32x4 accr[4][2] = {};
    for (int k0 = 0; k0 < KDIM; k0 += 64) {
        __syncthreads();
        #pragma unroll
        for (int it = 0; it < 4; ++it) {
            int f = t + 256 * it;
            int r = f >> 3, c = (f & 7) * 8;
            int row = m0 + r;
            uint4 v = make_uint4(0u, 0u, 0u, 0u);
            if (row < M) v = *reinterpret_cast<const uint4*>(&A[(size_t)row * KDIM + k0 + c]);
            *reinterpret_cast<uint4*>(&As[r * 72 + c]) = v;
        }
        #pragma unroll
        for (int it = 0; it < 2; ++it) {
            int f = t + 256 * it;
            int n = f >> 3, c = (f & 7) * 8;
            *reinterpret_cast<uint4*>(&Bls[n * 72 + c]) =
                *reinterpret_cast<const uint4*>(&WTl[(size_t)(n0 + n) * KDIM + k0 + c]);
            *reinterpret_cast<uint4*>(&Brs[n * 72 + c]) =
                *reinterpret_cast<const uint4*>(&WTr[(size_t)(n0 + n) * KDIM + k0 + c]);
        }
        __syncthreads();
        #pragma unroll
        for (int kk = 0; kk < 64; kk += 32) {
            bf16x8 af[4], bl[2], br[2];
            #pragma unroll
            for (int mi = 0; mi < 4; ++mi)
                af[mi] = *reinterpret_cast<const bf16x8*>(
                    &As[(wm * 64 + mi * 16 + l15) * 72 + kk + quad * 8]);
            #pragma unroll
            for (int ni = 0; ni < 2; ++ni) {
                bl[ni] = *reinterpret_cast<const bf16x8*>(
                    &Bls[(wn * 32 + ni * 16 + l15) * 72 + kk + quad * 8]);
                br[ni] = *reinterpret_cast<const bf16x8*>(
                    &Brs[(wn * 32 + ni * 16 + l15) * 72 + kk + quad * 8]);
            }
            #pragma unroll
            for (int mi = 0; mi < 4; ++mi)
                #pragma unroll
                for (int ni = 0; ni < 2; ++ni) {
                    accl[mi][ni] = __builtin_amdgcn_mfma_f32_16x16x32_bf16(
                        af[mi], bl[ni], accl[mi][ni], 0, 0, 0);
                    accr[mi][ni] = __builtin_amdgcn_mfma_f32_16x16x32_bf16(
                        af[mi], br[ni], accr[mi][ni], 0, 0, 0);
                }
        }
    }
    #pragma unroll
    for (int mi = 0; mi < 4; ++mi)
        #pragma unroll
        for (int ni = 0; ni < 2; ++ni)
            #pragma unroll
            for (int r = 0; r < 4; ++r) {
                int row = m0 + wm * 64 + mi * 16 + quad * 4 + r;
                int col = n0 + wn * 32 + ni * 16 + l15;
                if (row < M) {
                    Cl[(size_t)row * NC + col] = __float2bfloat16(accl[mi][ni][r]);
                    Cr[(size_t)row * NC + col] = __float2bfloat16(accr[mi][ni][r]);
                }
            }
}

// ---------------- layer 1: wave/node, 4 edges unrolled, DPP reduce, packed f32 ----
__global__ void k_node1(const __hip_bfloat16* __restrict__ xl,
                        const __hip_bfloat16* __restrict__ xr,
                        const int* __restrict__ rowstart, const int* __restrict__ csr_src,
                        const float* __restrict__ att,   // [4,64]
                        const float* __restrict__ bias,  // [64]
                        const float* __restrict__ lng,
                        const float* __restrict__ lnb,
                        __hip_bfloat16* __restrict__ h1b) {
    int wid = (blockIdx.x * 256 + threadIdx.x) >> 6;
    int lane = threadIdx.x & 63;
    if (wid >= NNODES) return;
    const int i = wid;
    const int grp = lane >> 4;
    const int c0 = (lane & 15) * 4;
    const int fb = lane * 4;

    uint2 rraw = *reinterpret_cast<const uint2*>(xr + (size_t)i * 256 + fb);
    v2f xr01 = bf2_to_f2(rraw.x), xr23 = bf2_to_f2(rraw.y);
    const float4 av = *reinterpret_cast<const float4*>(att + fb);
    v2f a01 = {av.x, av.y}, a23 = {av.z, av.w};

    v2f Lab = {0.f, 0.f}, Lcd = {0.f, 0.f};
    v2f Aa01 = {0.f, 0.f}, Aa23 = {0.f, 0.f};
    v2f Ab01 = {0.f, 0.f}, Ab23 = {0.f, 0.f};

    const int p0 = rowstart[i], p1 = rowstart[i + 1];
    for (int p = p0; p < p1; p += 4) {
        int q1 = (p + 1 < p1) ? p + 1 : p1 - 1;
        int q2 = (p + 2 < p1) ? p + 2 : p1 - 1;
        int q3 = (p + 3 < p1) ? p + 3 : p1 - 1;
        int j0 = csr_src[p];
        int j1 = csr_src[q1];
        int j2 = csr_src[q2];
        int j3 = csr_src[q3];
        uint2 g0 = *reinterpret_cast<const uint2*>(xl + (size_t)j0 * 256 + fb);
        uint2 g1 = *reinterpret_cast<const uint2*>(xl + (size_t)j1 * 256 + fb);
        uint2 g2 = *reinterpret_cast<const uint2*>(xl + (size_t)j2 * 256 + fb);
        uint2 g3 = *reinterpret_cast<const uint2*>(xl + (size_t)j3 * 256 + fb);
        v2f x001 = bf2_to_f2(g0.x), x023 = bf2_to_f2(g0.y);
        v2f x101 = bf2_to_f2(g1.x), x123 = bf2_to_f2(g1.y);
        v2f x201 = bf2_to_f2(g2.x), x223 = bf2_to_f2(g2.y);
        v2f x301 = bf2_to_f2(g3.x), x323 = bf2_to_f2(g3.y);
        float e0 = red16(edot2(x001, x023, xr01, xr23, a01, a23));
        float e1 = red16(edot2(x101, x123, xr01, xr23, a01, a23));
        float e2 = red16(edot2(x201, x223, xr01, xr23, a01, a23));
        float e3 = red16(edot2(x301, x323, xr01, xr23, a01, a23));
        float pe0 = __expf(fminf(e0, 60.f));
        float pe1 = (p + 1 < p1) ? __expf(fminf(e1, 60.f)) : 0.f;
        float pe2 = (p + 2 < p1) ? __expf(fminf(e2, 60.f)) : 0.f;
        float pe3 = (p + 3 < p1) ? __expf(fminf(e3, 60.f)) : 0.f;
        Lab += (v2f){pe0, pe1};
        Lcd += (v2f){pe2, pe3};
        Aa01 += x001 * pe0; Aa23 += x023 * pe0;
        Ab01 += x101 * pe1; Ab23 += x123 * pe1;
        Aa01 += x201 * pe2; Aa23 += x223 * pe2;
        Ab01 += x301 * pe3; Ab23 += x323 * pe3;
    }
    float l = (Lab.x + Lab.y) + (Lcd.x + Lcd.y);
    float inv = 1.f / (l + SM_EPS);
    v2f V01 = (Aa01 + Ab01) * inv;
    v2f V23 = (Aa23 + Ab23) * inv;
    float v0 = V01.x, v1 = V01.y, v2 = V23.x, v3 = V23.y;
    // mean over 4 heads (cross 16-lane groups -> shfl)
    v0 += __shfl_xor(v0, 16); v0 += __shfl_xor(v0, 32);
    v1 += __shfl_xor(v1, 16); v1 += __shfl_xor(v1, 32);
    v2 += __shfl_xor(v2, 16); v2 += __shfl_xor(v2, 32);
    v3 += __shfl_xor(v3, 16); v3 += __shfl_xor(v3, 32);
    const float4 bv = *reinterpret_cast<const float4*>(bias + c0);
    float o0 = v0 * 0.25f + bv.x;
    float o1 = v1 * 0.25f + bv.y;
    float o2 = v2 * 0.25f + bv.z;
    float o3 = v3 * 0.25f + bv.w;
    // LayerNorm over 64 ch (within 16-lane group -> DPP)
    float mu = red16(o0 + o1 + o2 + o3) * 0.015625f;
    float d0 = o0 - mu, d1 = o1 - mu, d2 = o2 - mu, d3 = o3 - mu;
    float ss = red16(d0 * d0 + d1 * d1 + d2 * d2 + d3 * d3);
    float istd = rsqrtf(ss * 0.015625f + LN_EPS);
    const float4 gv = *reinterpret_cast<const float4*>(lng + c0);
    const float4 bb = *reinterpret_cast<const float4*>(lnb + c0);
    float h0 = fmaxf(d0 * istd * gv.x + bb.x, 0.f);
    float h1 = fmaxf(d1 * istd * gv.y + bb.y, 0.f);
    float h2 = fmaxf(d2 * istd * gv.z + bb.z, 0.f);
    float h3 = fmaxf(d3 * istd * gv.w + bb.w, 0.f);
    if (grp == 0) {
        uint2 pk;
        pk.x = pack_bf2(h0, h1);
        pk.y = pack_bf2(h2, h3);
        *reinterpret_cast<uint2*>(h1b + (size_t)i * 64 + c0) = pk;
    }
}

// ---------------- layer 2: 16-lane group per edge, DPP reduce, packed, final LN ----
__global__ void k_node2(const __hip_bfloat16* __restrict__ xl,
                        const __hip_bfloat16* __restrict__ xr,
                        const int* __restrict__ rowstart, const int* __restrict__ csr_src,
                        const float* __restrict__ att,   // [64]
                        const float* __restrict__ bias,
                        const float* __restrict__ lng,
                        const float* __restrict__ lnb,
                        float* __restrict__ out) {
    int wid = (blockIdx.x * 256 + threadIdx.x) >> 6;
    int lane = threadIdx.x & 63;
    if (wid >= NNODES) return;
    const int i = wid;
    const int grp = lane >> 4;
    const int c0 = (lane & 15) * 4;

    uint2 rraw = *reinterpret_cast<const uint2*>(xr + (size_t)i * 64 + c0);
    v2f xr01 = bf2_to_f2(rraw.x), xr23 = bf2_to_f2(rraw.y);
    const float4 av = *reinterpret_cast<const float4*>(att + c0);
    v2f a01 = {av.x, av.y}, a23 = {av.z, av.w};
    float l = 0.f;
    v2f A01 = {0.f, 0.f}, A23 = {0.f, 0.f};

    const int p0 = rowstart[i], p1 = rowstart[i + 1];
    for (int p = p0; p < p1; p += 4) {
        int pe = p + grp;
        bool valid = pe < p1;
        int j = csr_src[valid ? pe : p1 - 1];
        uint2 g = *reinterpret_cast<const uint2*>(xl + (size_t)j * 64 + c0);
        v2f x01 = bf2_to_f2(g.x), x23 = bf2_to_f2(g.y);
        float e = red16(edot2(x01, x23, xr01, xr23, a01, a23));
        float w = valid ? __expf(fminf(e, 60.f)) : 0.f;
        l += w;
        A01 += x01 * w;
        A23 += x23 * w;
    }
    // sum partial states across the 4 groups (plain adds)
    #pragma unroll
    for (int s = 16; s <= 32; s <<= 1) {
        l     += __shfl_xor(l, s);
        A01.x += __shfl_xor(A01.x, s);
        A01.y += __shfl_xor(A01.y, s);
        A23.x += __shfl_xor(A23.x, s);
        A23.y += __shfl_xor(A23.y, s);
    }
    float inv = 1.f / (l + SM_EPS);
    const float4 bv = *reinterpret_cast<const float4*>(bias + c0);
    float o0 = A01.x * inv + bv.x;
    float o1 = A01.y * inv + bv.y;
    float o2 = A23.x * inv + bv.z;
    float o3 = A23.y * inv + bv.w;
    float mu = red16(o0 + o1 + o2 + o3) * 0.015625f;
    float d0 = o0 - mu, d1 = o1 - mu, d2 = o2 - mu, d3 = o3 - mu;
    float ss = red16(d0 * d0 + d1 * d1 + d2 * d2 + d3 * d3);
    float istd = rsqrtf(ss * 0.015625f + LN_EPS);
    const float4 gv = *reinterpret_cast<const float4*>(lng + c0);
    const float4 bb = *reinterpret_cast<const float4*>(lnb + c0);
    if (grp == 0) {
        float4 y;
        y.x = d0 * istd * gv.x + bb.x;
        y.y = d1 * istd * gv.y + bb.y;
        y.z = d2 * istd * gv.z + bb.z;
        y.w = d3 * istd * gv.w + bb.w;
        *reinterpret_cast<float4*>(out + (size_t)i * 64 + c0) = y;
    }
}

extern "C" void kernel_launch(void* const* d_in, const int* in_sizes, int n_in,
                              void* d_out, int out_size, void* d_ws, size_t ws_size,
                              hipStream_t stream) {
    const float* x    = (const float*)d_in[0];
    const int*   ei   = (const int*)d_in[1];
    const float* W1l  = (const float*)d_in[2];
    const float* W1r  = (const float*)d_in[3];
    const float* att1 = (const float*)d_in[4];
    const float* b1   = (const float*)d_in[5];
    const float* ln1g = (const float*)d_in[6];
    const float* ln1b = (const float*)d_in[7];
    const float* W2l  = (const float*)d_in[8];
    const float* W2r  = (const float*)d_in[9];
    const float* att2 = (const float*)d_in[10];
    const float* b2   = (const float*)d_in[11];
    const float* ln2g = (const float*)d_in[12];
    const float* ln2b = (const float*)d_in[13];
    float* out = (float*)d_out;

    char* w = (char*)d_ws;
    size_t off = 0;
    auto alloc = [&](size_t bytes) -> void* {
        void* p = w + off;
        off += (bytes + 255) & ~(size_t)255;
        return p;
    };
    __hip_bfloat16* xb   = (__hip_bfloat16*)alloc((size_t)NNODES * 256 * 2);
    __hip_bfloat16* xl1  = (__hip_bfloat16*)alloc((size_t)NNODES * 256 * 2);
    __hip_bfloat16* xr1  = (__hip_bfloat16*)alloc((size_t)NNODES * 256 * 2);
    __hip_bfloat16* h1b  = (__hip_bfloat16*)alloc((size_t)NNODES * 64 * 2);
    __hip_bfloat16* xl2  = (__hip_bfloat16*)alloc((size_t)NNODES * 64 * 2);
    __hip_bfloat16* xr2  = (__hip_bfloat16*)alloc((size_t)NNODES * 64 * 2);
    __hip_bfloat16* w1lT = (__hip_bfloat16*)alloc(256 * 256 * 2);
    __hip_bfloat16* w1rT = (__hip_bfloat16*)alloc(256 * 256 * 2);
    __hip_bfloat16* w2lT = (__hip_bfloat16*)alloc(64 * 64 * 2);
    __hip_bfloat16* w2rT = (__hip_bfloat16*)alloc(64 * 64 * 2);
    int* deg      = (int*)alloc((size_t)NNODES * 4);
    int* rowstart = (int*)alloc((size_t)(NNODES + 1) * 4);
    int* cursor   = (int*)alloc((size_t)NNODES * 4);
    int* csr_src  = (int*)alloc((size_t)ETOT * 4);
    int* blocksum = (int*)alloc(1024);
    (void)ws_size; (void)in_sizes; (void)n_in; (void)out_size;

    // prep: zero deg + cast x + cast/transpose weights (one kernel)
    k_cast_all<<<6794, 256, 0, stream>>>(x, xb, W1l, W1r, W2l, W2r,
                                         w1lT, w1rT, w2lT, w2rT, deg);

    const int histB = (ETOT + 255) / 256;
    const int scanB = (NNODES + 255) / 256;
    k_hist<<<histB, 256, 0, stream>>>(ei, deg);
    k_scan1<<<scanB, 256, 0, stream>>>(deg, rowstart, blocksum);
    k_scan2<<<1, 256, 0, stream>>>(blocksum, scanB);
    k_scan3<<<scanB, 256, 0, stream>>>(rowstart, blocksum, cursor);
    k_scatter<<<histB, 256, 0, stream>>>(ei, cursor, csr_src);

    dim3 gm1((NNODES + 127) / 128, 4);
    k_gemm_dual<256, 256><<<gm1, 256, 0, stream>>>(xb, w1lT, w1rT, xl1, xr1, NNODES);
    k_node1<<<(NNODES + 3) / 4, 256, 0, stream>>>(xl1, xr1, rowstart, csr_src,
                                                  att1, b1, ln1g, ln1b, h1b);
    dim3 gm2((NNODES + 127) / 128, 1);
    k_gemm_dual<64, 64><<<gm2, 256, 0, stream>>>(h1b, w2lT, w2rT, xl2, xr2, NNODES);
    k_node2<<<(NNODES + 3) / 4, 256, 0, stream>>>(xl2, xr2, rowstart, csr_src,
                                                  att2, b2, ln2g, ln2b, out);
}